// Round 16
// baseline (221.603 us; speedup 1.0000x reference)
//
#include <hip/hip_runtime.h>
#include <hip/hip_bf16.h>

#define NB 2
#define NT 2048
#define NC 1024
#define NHD 16
#define HDD 64
#define LOG2E 1.4426950408889634f

typedef __attribute__((ext_vector_type(8))) short short8;
typedef __attribute__((ext_vector_type(4))) short short4v;
typedef __attribute__((ext_vector_type(4))) float f32x4;
typedef __attribute__((ext_vector_type(16))) float f32x16;

__device__ __forceinline__ ushort f2bf(float f) {
    union { float f; unsigned u; } v; v.f = f;
    unsigned u = v.u;
    unsigned r = (u + 0x7FFFu + ((u >> 16) & 1u)) >> 16;
    return (ushort)r;
}

__device__ __forceinline__ float bf2f(ushort u) {
    unsigned x = ((unsigned)u) << 16;
    float f; __builtin_memcpy(&f, &x, 4); return f;
}

__device__ __forceinline__ unsigned pkbf(float a, float b) {
    __hip_bfloat162 t = __float22bfloat162_rn(float2{a, b});
    unsigned u; __builtin_memcpy(&u, &t, 4); return u;
}

__device__ __forceinline__ void gload16(const ushort* g, ushort* l) {
    __builtin_amdgcn_global_load_lds((const __attribute__((address_space(1))) void*)g,
                                     (__attribute__((address_space(3))) void*)l, 16, 0, 0);
}

// ---------------- fused prep: x->bf16 + 3 weight transposes ----------------
__device__ __forceinline__ void tcvt_tile(const float* __restrict__ src, ushort* __restrict__ dst,
                                          int Kd, int Nd, int kb, int nb)
{
    __shared__ ushort tile[64][68];
    const int tid = threadIdx.x;
    const int r = tid >> 2, c = (tid & 3) * 16;
    const float* sp = src + (size_t)(kb + r) * Nd + nb + c;
#pragma unroll
    for (int i = 0; i < 16; i += 4) {
        float4 v = *(const float4*)(sp + i);
        tile[r][c + i + 0] = f2bf(v.x);
        tile[r][c + i + 1] = f2bf(v.y);
        tile[r][c + i + 2] = f2bf(v.z);
        tile[r][c + i + 3] = f2bf(v.w);
    }
    __syncthreads();
    ushort* dp = dst + (size_t)(nb + r) * Kd + kb + c;
#pragma unroll
    for (int i = 0; i < 16; i += 8) {
        short8 o;
#pragma unroll
        for (int j = 0; j < 8; j++) o[j] = (short)tile[c + i + j][r];
        *(short8*)(dp + i) = o;
    }
}

__global__ __launch_bounds__(256)
void prep(const float* __restrict__ x, const float* __restrict__ q_w,
          const float* __restrict__ kv_w, const float* __restrict__ o_w,
          ushort* __restrict__ xb, ushort* __restrict__ wqkvT, ushort* __restrict__ woT)
{
    const int bid = blockIdx.x;
    if (bid < 2048) {                       // cvtx: 2048 blocks
        int i = (bid * 256 + threadIdx.x) * 8;
        float4 a = *(const float4*)(x + i);
        float4 b = *(const float4*)(x + i + 4);
        short8 o;
        o[0] = (short)f2bf(a.x); o[1] = (short)f2bf(a.y);
        o[2] = (short)f2bf(a.z); o[3] = (short)f2bf(a.w);
        o[4] = (short)f2bf(b.x); o[5] = (short)f2bf(b.y);
        o[6] = (short)f2bf(b.z); o[7] = (short)f2bf(b.w);
        *(short8*)(xb + i) = o;
    } else if (bid < 2304) {                // q_w: 16x16
        int r = bid - 2048;
        tcvt_tile(q_w, wqkvT, 1024, 1024, (r & 15) * 64, (r >> 4) * 64);
    } else if (bid < 2816) {                // kv_w: 16x32
        int r = bid - 2304;
        tcvt_tile(kv_w, wqkvT + 1024 * 1024, 1024, 2048, (r & 15) * 64, (r >> 4) * 64);
    } else {                                // o_w: 16x16
        int r = bid - 2816;
        tcvt_tile(o_w, woT, 1024, 1024, (r & 15) * 64, (r >> 4) * 64);
    }
}

// ---------------- 128x128 bf16 MFMA GEMM (R13-proven form, unchanged) ----------------
template<int MODE>
__global__ __launch_bounds__(256)
void gemm128(const ushort* __restrict__ A, const ushort* __restrict__ Bt,
             const float* __restrict__ bias0, const float* __restrict__ bias1,
             ushort* __restrict__ Qo, ushort* __restrict__ Ko, ushort* __restrict__ VoT,
             float* __restrict__ Fo, int Kdim)
{
    __shared__ ushort Al[2][128 * 32];
    __shared__ ushort Bl[2][128 * 32];
    const int tid = threadIdx.x;
    const int lane = tid & 63, w = tid >> 6;
    const int wr = (w >> 1) * 64, wc = (w & 1) * 64;
    const int lg = lane >> 4, lc = lane & 15;

    const int nwg = gridDim.x;
    const int cpx = nwg >> 3;
    const int sid = (blockIdx.x & 7) * cpx + (blockIdx.x >> 3);
    const int bm = (sid & 31) * 128, bn = (sid >> 5) * 128;

    f32x4 acc[4][4] = {};

    const int srow = lane >> 2, scol = (lane & 3) * 8;
    const int seg0 = w * 2;

    const ushort* apb = A  + (size_t)(bm + seg0 * 16 + srow) * Kdim + scol;
    const ushort* bpb = Bt + (size_t)(bn + seg0 * 16 + srow) * Kdim + scol;

    gload16(apb,              &Al[0][seg0 * 512]);
    gload16(apb + 16 * Kdim,  &Al[0][(seg0 + 1) * 512]);
    gload16(bpb,              &Bl[0][seg0 * 512]);
    gload16(bpb + 16 * Kdim,  &Bl[0][(seg0 + 1) * 512]);

    int cur = 0;
    for (int k0 = 0; k0 < Kdim; k0 += 32) {
        __syncthreads();
        if (k0 + 32 < Kdim) {
            gload16(apb + (k0 + 32),             &Al[cur ^ 1][seg0 * 512]);
            gload16(apb + (k0 + 32) + 16 * Kdim, &Al[cur ^ 1][(seg0 + 1) * 512]);
            gload16(bpb + (k0 + 32),             &Bl[cur ^ 1][seg0 * 512]);
            gload16(bpb + (k0 + 32) + 16 * Kdim, &Bl[cur ^ 1][(seg0 + 1) * 512]);
        }
        short8 af[4], bfv[4];
#pragma unroll
        for (int mt = 0; mt < 4; mt++) af[mt] = *(const short8*)&Al[cur][(wr + mt*16 + lc) * 32 + lg*8];
#pragma unroll
        for (int nt = 0; nt < 4; nt++) bfv[nt] = *(const short8*)&Bl[cur][(wc + nt*16 + lc) * 32 + lg*8];
        __builtin_amdgcn_s_setprio(1);
#pragma unroll
        for (int mt = 0; mt < 4; mt++)
#pragma unroll
            for (int nt = 0; nt < 4; nt++)
                acc[mt][nt] = __builtin_amdgcn_mfma_f32_16x16x32_bf16(af[mt], bfv[nt], acc[mt][nt], 0, 0, 0);
        __builtin_amdgcn_s_setprio(0);
        cur ^= 1;
    }

#pragma unroll
    for (int mt = 0; mt < 4; mt++) {
#pragma unroll
        for (int nt = 0; nt < 4; nt++) {
            const int n = bn + wc + nt * 16 + lc;
            const int mb = bm + wr + mt * 16 + lg * 4;
            if (MODE == 1) {
#pragma unroll
                for (int rr = 0; rr < 4; rr++)
                    Fo[(size_t)(mb + rr) * NC + n] = acc[mt][nt][rr] + bias0[n];
            } else {
                const int b = mb >> 11, t = mb & 2047;
                const int reg = n >> 10;            // 0=Q, 1=K, 2=V (uniform per nt)
                if (reg == 0) {
                    int hh = n >> 6, d = n & 63;
                    ushort* qp = Qo + (((size_t)b * NHD + hh) * NT + t) * HDD + d;
#pragma unroll
                    for (int rr = 0; rr < 4; rr++)
                        qp[rr * HDD] = f2bf((acc[mt][nt][rr] + bias0[n]) * (0.125f * LOG2E));
                } else if (reg == 1) {
                    int j = n - NC;
                    int hh = j >> 6, d = j & 63;
                    ushort* kp = Ko + (((size_t)b * NHD + hh) * NT + t) * HDD + d;
#pragma unroll
                    for (int rr = 0; rr < 4; rr++)
                        kp[rr * HDD] = f2bf(acc[mt][nt][rr] + bias1[j]);
                } else {                            // V -> transposed, packed store
                    int j = n - NC;
                    int jj = j - 1024;
                    int hh = jj >> 6, d = jj & 63;
                    short4v o;
#pragma unroll
                    for (int rr = 0; rr < 4; rr++)
                        o[rr] = (short)f2bf(acc[mt][nt][rr] + bias1[j]);
                    *(short4v*)&VoT[(((size_t)b * NHD + hh) * HDD + d) * NT + t] = o;
                }
            }
        }
    }
}

// ---- per-q-tile softmax+PV step as a MACRO on NAMED scalar f32x16 accumulators.
// (R14 passed acc/bb by pointer -> address-taken -> scratch spill, FETCH+WRITE
// exploded. Macro + static indexing keeps everything in VGPRs.)
#define QSTEP(QF, MS, LS, ACC0, ACC1, QOFF)                                        \
  do {                                                                             \
    f32x16 S = {};                                                                 \
    __builtin_amdgcn_s_setprio(1);                                                 \
    S = __builtin_amdgcn_mfma_f32_32x32x16_bf16(                                   \
        *(const short8*)&Kl[(sub*32+lo5)*72 + 0*16 + 8*hi], QF[0], S, 0, 0, 0);    \
    S = __builtin_amdgcn_mfma_f32_32x32x16_bf16(                                   \
        *(const short8*)&Kl[(sub*32+lo5)*72 + 1*16 + 8*hi], QF[1], S, 0, 0, 0);    \
    S = __builtin_amdgcn_mfma_f32_32x32x16_bf16(                                   \
        *(const short8*)&Kl[(sub*32+lo5)*72 + 2*16 + 8*hi], QF[2], S, 0, 0, 0);    \
    S = __builtin_amdgcn_mfma_f32_32x32x16_bf16(                                   \
        *(const short8*)&Kl[(sub*32+lo5)*72 + 3*16 + 8*hi], QF[3], S, 0, 0, 0);    \
    __builtin_amdgcn_s_setprio(0);                                                 \
    const float sk = slope2 * (float)kv0s;                                         \
    float mloc = MS - sk;                                                          \
    if (kv0s + 31 > q0w + (QOFF)) {                                                \
      _Pragma("unroll")                                                            \
      for (int r = 0; r < 16; r++) {                                               \
        int kvr = kv0s + (r & 3) + 8 * (r >> 2) + 4 * hi;                          \
        S[r] = (kvr > qlA + (QOFF)) ? -1e30f : (S[r] + bb[r]);                     \
      }                                                                            \
    } else {                                                                       \
      _Pragma("unroll")                                                            \
      for (int r = 0; r < 16; r++) S[r] = S[r] + bb[r];                            \
    }                                                                              \
    float a0 = fmaxf(fmaxf(S[0], S[1]), S[2]);                                     \
    float a1 = fmaxf(fmaxf(S[3], S[4]), S[5]);                                     \
    float a2 = fmaxf(fmaxf(S[6], S[7]), S[8]);                                     \
    float a3 = fmaxf(fmaxf(S[9], S[10]), S[11]);                                   \
    float a4 = fmaxf(fmaxf(S[12], S[13]), S[14]);                                  \
    float rmax = fmaxf(fmaxf(fmaxf(a0, a1), fmaxf(a2, a3)), fmaxf(a4, S[15]));     \
    rmax = fmaxf(rmax, __shfl_xor(rmax, 32));                                      \
    if (__any(rmax - mloc > 8.0f)) {                                               \
      float mn = fmaxf(mloc, rmax);                                                \
      float sc = __builtin_amdgcn_exp2f(mloc - mn);                                \
      mloc = mn;                                                                   \
      LS *= sc;                                                                    \
      _Pragma("unroll")                                                            \
      for (int r = 0; r < 16; r++) { ACC0[r] *= sc; ACC1[r] *= sc; }               \
    }                                                                              \
    MS = mloc + sk;                                                                \
    _Pragma("unroll")                                                              \
    for (int r = 0; r < 16; r++) S[r] = __builtin_amdgcn_exp2f(S[r] - mloc);       \
    unsigned pw0 = pkbf(S[0], S[1]),   pw1 = pkbf(S[2], S[3]);                     \
    unsigned pw2 = pkbf(S[4], S[5]),   pw3 = pkbf(S[6], S[7]);                     \
    unsigned pw4 = pkbf(S[8], S[9]),   pw5 = pkbf(S[10], S[11]);                   \
    unsigned pw6 = pkbf(S[12], S[13]), pw7 = pkbf(S[14], S[15]);                   \
    asm volatile("v_permlane32_swap_b32 %0, %1" : "+v"(pw0), "+v"(pw2));           \
    asm volatile("v_permlane32_swap_b32 %0, %1" : "+v"(pw1), "+v"(pw3));           \
    asm volatile("v_permlane32_swap_b32 %0, %1" : "+v"(pw4), "+v"(pw6));           \
    asm volatile("v_permlane32_swap_b32 %0, %1" : "+v"(pw5), "+v"(pw7));           \
    union { unsigned u[4]; short8 s; } fa0, fa1;                                   \
    fa0.u[0] = pw0; fa0.u[1] = pw1; fa0.u[2] = pw2; fa0.u[3] = pw3;                \
    fa1.u[0] = pw4; fa1.u[1] = pw5; fa1.u[2] = pw6; fa1.u[3] = pw7;                \
    f32x16 z = {};                                                                 \
    __builtin_amdgcn_s_setprio(1);                                                 \
    z = __builtin_amdgcn_mfma_f32_32x32x16_bf16(ones, fa0.s, z, 0, 0, 0);          \
    z = __builtin_amdgcn_mfma_f32_32x32x16_bf16(ones, fa1.s, z, 0, 0, 0);          \
    {                                                                              \
      short8 vf00 = *(const short8*)&Vl[(0*32+lo5)*72 + sub*32 + 8*hi];            \
      short8 vf01 = *(const short8*)&Vl[(0*32+lo5)*72 + sub*32 + 16 + 8*hi];       \
      short8 vf10 = *(const short8*)&Vl[(1*32+lo5)*72 + sub*32 + 8*hi];            \
      short8 vf11 = *(const short8*)&Vl[(1*32+lo5)*72 + sub*32 + 16 + 8*hi];       \
      ACC0 = __builtin_amdgcn_mfma_f32_32x32x16_bf16(vf00, fa0.s, ACC0, 0, 0, 0);  \
      ACC0 = __builtin_amdgcn_mfma_f32_32x32x16_bf16(vf01, fa1.s, ACC0, 0, 0, 0);  \
      ACC1 = __builtin_amdgcn_mfma_f32_32x32x16_bf16(vf10, fa0.s, ACC1, 0, 0, 0);  \
      ACC1 = __builtin_amdgcn_mfma_f32_32x32x16_bf16(vf11, fa1.s, ACC1, 0, 0, 0);  \
    }                                                                              \
    __builtin_amdgcn_s_setprio(0);                                                 \
    LS += z[0];                                                                    \
  } while (0)

// ---------------- flash attention: 64 q-rows/wave (2 q-tiles), 256 q/block ----------------
// 20 slots x 32 bh = 640 blocks. Staged tiles per bh: 272 -> 144 (-47%).
__global__ __launch_bounds__(256, 3)
void attn_fwd(const ushort* __restrict__ Q, const ushort* __restrict__ K,
              const ushort* __restrict__ Vt, ushort* __restrict__ Y,
              ushort* __restrict__ pool0, ushort* __restrict__ pool1,
              float* __restrict__ mlb)
{
    __shared__ ushort sb[2 * 2 * 64 * 72];        // 2 buffers x (K + V^T)

    const int tid = threadIdx.x;
    const int lane = tid & 63, w = tid >> 6;
    const int lo5 = lane & 31, hi = lane >> 5;
    const int slot = (int)(blockIdx.x >> 5);
    const int bh = blockIdx.x & 31;
    const int b = bh >> 4, h = bh & 15;

    // slot -> (qc, seg, nseg); heavy-first
    int qc, seg, nseg;
    if (slot < 8)       { qc = 7 - (slot >> 2); seg = slot & 3; nseg = 4; }
    else if (slot < 14) { int u = slot - 8; int q3 = u / 3; qc = 5 - q3; seg = u - q3 * 3; nseg = 3; }
    else if (slot < 18) { int u = slot - 14; qc = 3 - (u >> 1); seg = u & 1; nseg = 2; }
    else                { qc = 19 - slot; seg = 0; nseg = 1; }
    const int T = 4 * qc + 4;
    const int t_begin = (seg * T) / nseg;
    const int t_end   = ((seg + 1) * T) / nseg;
    const bool split = (nseg > 1);
    int pi = 0;
    if (split) {
        int pbase = (qc == 7) ? 0 : (qc == 6) ? 4 : (qc == 5) ? 8 : (qc == 4) ? 11 : (qc == 3) ? 14 : 16;
        pi = bh * 18 + pbase + seg;
    }

    const ushort* Qp = Q + (size_t)bh * NT * HDD;
    const ushort* Kp = K + (size_t)bh * NT * HDD;
    const ushort* Vp = Vt + (size_t)bh * HDD * NT;

    const int q0w = qc * 256 + w * 64;     // wave's 64 q rows (A: +0..31, B: +32..63)
    const int qlA = q0w + lo5;

    const float slope2 = (float)(h + 1) * (LOG2E / (float)NHD);

    short8 qfA[4], qfB[4];
    {
        const ushort* qr = Qp + (size_t)qlA * HDD + 8 * hi;
#pragma unroll
        for (int kk = 0; kk < 4; kk++) qfA[kk] = *(const short8*)(qr + kk * 16);
        const ushort* qr2 = qr + 32 * HDD;
#pragma unroll
        for (int kk = 0; kk < 4; kk++) qfB[kk] = *(const short8*)(qr2 + kk * 16);
    }

    short8 ones;
#pragma unroll
    for (int j = 0; j < 8; j++) ones[j] = (short)0x3F80;

    // ALiBi bias, row-constant (-slope*q) term dropped (softmax-shift-invariant):
    // bb depends only on the in-tile kv offset -> shared by both q-tiles.
    float bb[16];
#pragma unroll
    for (int r = 0; r < 16; r++) {
        int roff = (r & 3) + 8 * (r >> 2) + 4 * hi;
        bb[r] = slope2 * (float)roff;
    }

    float m_a = -1e30f, l_a = 0.f, m_b = -1e30f, l_b = 0.f;
    f32x16 accA0 = {}, accA1 = {}, accB0 = {}, accB1 = {};

    const int sr = tid >> 2, sd = (tid & 3) * 16;

    // prefetch first tile
    short8 pk0, pk1, pv0, pv1;
    {
        const ushort* kp = Kp + (size_t)(t_begin * 64 + sr) * HDD + sd;
        pk0 = *(const short8*)kp;
        pk1 = *(const short8*)(kp + 8);
        const ushort* vp = Vp + (size_t)sr * NT + t_begin * 64 + sd;
        pv0 = *(const short8*)vp;
        pv1 = *(const short8*)(vp + 8);
    }

    for (int t = t_begin; t < t_end; t++) {
        const int kv0 = t * 64;
        ushort* Kl = sb + ((t - t_begin) & 1) * 2 * 64 * 72;
        ushort* Vl = Kl + 64 * 72;
        *(short8*)&Kl[sr * 72 + sd]     = pk0;
        *(short8*)&Kl[sr * 72 + sd + 8] = pk1;
        *(short8*)&Vl[sr * 72 + sd]     = pv0;
        *(short8*)&Vl[sr * 72 + sd + 8] = pv1;
        __syncthreads();                          // single barrier per tile (dbuf)

        if (t + 1 < t_end) {
            const int kv1 = kv0 + 64;
            const ushort* kp = Kp + (size_t)(kv1 + sr) * HDD + sd;
            pk0 = *(const short8*)kp;
            pk1 = *(const short8*)(kp + 8);
            const ushort* vp = Vp + (size_t)sr * NT + kv1 + sd;
            pv0 = *(const short8*)vp;
            pv1 = *(const short8*)(vp + 8);
        }

#pragma unroll
        for (int sub = 0; sub < 2; sub++) {
            const int kv0s = kv0 + sub * 32;
            if (kv0s > q0w + 63) continue;         // past tile B's diagonal (wave-uniform)
            if (kv0s <= q0w + 31)                  // tile A
                QSTEP(qfA, m_a, l_a, accA0, accA1, 0);
            // tile B (guaranteed kv0s <= q0w+63 = q0B+31)
            QSTEP(qfB, m_b, l_b, accB0, accB1, 32);
        }
    }

    // ---- epilogue ----
    const float invA = split ? 1.0f : __builtin_amdgcn_rcpf(l_a);
    const float invB = split ? 1.0f : __builtin_amdgcn_rcpf(l_b);
    __syncthreads();
    ushort* myO = sb + w * 64 * 72;               // [64 q][72] per wave
#pragma unroll
    for (int r = 0; r < 16; r++) {
        int d0 = (r & 3) + 8 * (r >> 2) + 4 * hi;
        myO[lo5 * 72 + d0]             = f2bf(accA0[r] * invA);
        myO[lo5 * 72 + 32 + d0]        = f2bf(accA1[r] * invA);
        myO[(32 + lo5) * 72 + d0]      = f2bf(accB0[r] * invB);
        myO[(32 + lo5) * 72 + 32 + d0] = f2bf(accB1[r] * invB);
    }
    if (split && hi == 0) {
        int base = pi * 512 + w * 64 + lo5;
        mlb[base]            = m_a;
        mlb[base + 32]       = m_b;
        mlb[base + 256]      = l_a;
        mlb[base + 256 + 32] = l_b;
    }
    __syncthreads();
    const int orow = lane >> 1, ocol = (lane & 1) * 32;
#pragma unroll
    for (int ro = 0; ro < 2; ro++) {
        const int row = ro * 32 + orow;           // 0..63 within wave
        if (split) {
            ushort* pp = (pi < 192 ? pool0 + (size_t)pi * 16384
                                   : pool1 + (size_t)(pi - 192) * 16384)
                         + (w * 64 + row) * 64 + ocol;
#pragma unroll
            for (int c = 0; c < 4; c++)
                *(short8*)(pp + c * 8) = *(const short8*)&myO[row * 72 + ocol + c * 8];
        } else {
            ushort* yp = Y + ((size_t)b * NT + q0w + row) * NC + h * HDD + ocol;
#pragma unroll
            for (int c = 0; c < 4; c++)
                *(short8*)(yp + c * 8) = *(const short8*)&myO[row * 72 + ocol + c * 8];
        }
    }
}

// ---------------- combine split-KV partials (2-4 parts, 256 rows) ----------------
// grid 192: one block per (bh, qc in [2,7])
__global__ __launch_bounds__(256)
void combine(const ushort* __restrict__ pool0, const ushort* __restrict__ pool1,
             const float* __restrict__ mlb, ushort* __restrict__ Y)
{
    const int cb = blockIdx.x;
    const int bh = cb / 6, qs = cb % 6;
    const int qc = 7 - qs;
    const int b = bh >> 4, h = bh & 15;
    const int nseg = (qs < 2) ? 4 : (qs < 4) ? 3 : 2;
    const int pbase = (qs == 0) ? 0 : (qs == 1) ? 4 : (qs == 2) ? 8 : (qs == 3) ? 11 : (qs == 4) ? 14 : 16;
    const int pi0 = bh * 18 + pbase;

    const int r = threadIdx.x;                    // 0..255 rows

    float m[4], l[4], a[4];
    float M = -1e30f;
    for (int s = 0; s < nseg; s++) {
        m[s] = mlb[(pi0 + s) * 512 + r];
        l[s] = mlb[(pi0 + s) * 512 + 256 + r];
        M = fmaxf(M, m[s]);
    }
    float L = 0.f;
    for (int s = 0; s < nseg; s++) { a[s] = __builtin_amdgcn_exp2f(m[s] - M); L += a[s] * l[s]; }
    const float inv = __builtin_amdgcn_rcpf(L);

    const ushort* pp[4];
    for (int s = 0; s < nseg; s++) {
        int pi = pi0 + s;
        pp[s] = (pi < 192 ? pool0 + (size_t)pi * 16384 : pool1 + (size_t)(pi - 192) * 16384) + r * 64;
    }
    ushort* yp = Y + ((size_t)b * NT + qc * 256 + r) * NC + h * HDD;

#pragma unroll
    for (int c = 0; c < 8; c++) {
        float acc[8] = {};
        for (int s = 0; s < nseg; s++) {
            short8 u = *(const short8*)(pp[s] + c * 8);
#pragma unroll
            for (int j = 0; j < 8; j++) acc[j] += a[s] * bf2f((ushort)u[j]);
        }
        short8 o;
#pragma unroll
        for (int j = 0; j < 8; j++) o[j] = (short)f2bf(acc[j] * inv);
        *(short8*)(yp + c * 8) = o;
    }
}

extern "C" void kernel_launch(void* const* d_in, const int* in_sizes, int n_in,
                              void* d_out, int out_size, void* d_ws, size_t ws_size,
                              hipStream_t stream)
{
    const float* x    = (const float*)d_in[0];
    const float* q_w  = (const float*)d_in[1];
    const float* q_b  = (const float*)d_in[2];
    const float* kv_w = (const float*)d_in[3];
    const float* kv_b = (const float*)d_in[4];
    const float* o_w  = (const float*)d_in[5];
    const float* o_b  = (const float*)d_in[6];
    float* out = (float*)d_out;

    char* ws = (char*)d_ws;
    ushort* xb    = (ushort*)(ws);                 // 8 MB (x bf16; read by gemm0)
    ushort* wqkvT = (ushort*)(ws + 8388608);       // 6 MB (weights; reused: pool0, 192x32KB)
    ushort* woT   = (ushort*)(ws + 14680064);      // 2 MB
    ushort* Qs    = (ushort*)(ws + 16777216);
    ushort* Ks    = (ushort*)(ws + 25165824);
    ushort* VsT   = (ushort*)(ws + 33554432);      // 8 MB: V^T written by gemm0 epilogue
    ushort* Ys    = (ushort*)(ws + 41943040);
    ushort* pool0 = wqkvT;                         // 192 slots x 32KB (6 MB exactly)
    ushort* pool1 = (ushort*)out;                  // 384 slots x 32KB in d_out (12 MB)
    float*  mlb   = (float*)((char*)out + 12582912);   // 576 x 512 f32 (1.2 MB)

    prep<<<3072, 256, 0, stream>>>(x, q_w, kv_w, o_w, xb, wqkvT, woT);
    gemm128<0><<<768, 256, 0, stream>>>(xb, wqkvT, q_b, kv_b, Qs, Ks, VsT, nullptr, 1024);
    attn_fwd<<<640, 256, 0, stream>>>(Qs, Ks, VsT, Ys, pool0, pool1, mlb);
    combine<<<192, 256, 0, stream>>>(pool0, pool1, mlb, Ys);
    gemm128<1><<<256, 256, 0, stream>>>(Ys, woT, o_b, nullptr, nullptr, nullptr, nullptr, out, 1024);
}

// Round 17
// 147.506 us; speedup vs baseline: 1.5023x; 1.5023x over previous
//
#include <hip/hip_runtime.h>
#include <hip/hip_bf16.h>

#define NB 2
#define NT 2048
#define NC 1024
#define NHD 16
#define HDD 64
#define LOG2E 1.4426950408889634f

typedef __attribute__((ext_vector_type(8))) short short8;
typedef __attribute__((ext_vector_type(4))) short short4v;
typedef __attribute__((ext_vector_type(4))) float f32x4;
typedef __attribute__((ext_vector_type(16))) float f32x16;

__device__ __forceinline__ ushort f2bf(float f) {
    union { float f; unsigned u; } v; v.f = f;
    unsigned u = v.u;
    unsigned r = (u + 0x7FFFu + ((u >> 16) & 1u)) >> 16;
    return (ushort)r;
}

__device__ __forceinline__ float bf2f(ushort u) {
    unsigned x = ((unsigned)u) << 16;
    float f; __builtin_memcpy(&f, &x, 4); return f;
}

__device__ __forceinline__ unsigned pkbf(float a, float b) {
    __hip_bfloat162 t = __float22bfloat162_rn(float2{a, b});
    unsigned u; __builtin_memcpy(&u, &t, 4); return u;
}

__device__ __forceinline__ void gload16(const ushort* g, ushort* l) {
    __builtin_amdgcn_global_load_lds((const __attribute__((address_space(1))) void*)g,
                                     (__attribute__((address_space(3))) void*)l, 16, 0, 0);
}

// ---------------- fused prep: x->bf16 + 3 weight transposes ----------------
__device__ __forceinline__ void tcvt_tile(const float* __restrict__ src, ushort* __restrict__ dst,
                                          int Kd, int Nd, int kb, int nb)
{
    __shared__ ushort tile[64][68];
    const int tid = threadIdx.x;
    const int r = tid >> 2, c = (tid & 3) * 16;
    const float* sp = src + (size_t)(kb + r) * Nd + nb + c;
#pragma unroll
    for (int i = 0; i < 16; i += 4) {
        float4 v = *(const float4*)(sp + i);
        tile[r][c + i + 0] = f2bf(v.x);
        tile[r][c + i + 1] = f2bf(v.y);
        tile[r][c + i + 2] = f2bf(v.z);
        tile[r][c + i + 3] = f2bf(v.w);
    }
    __syncthreads();
    ushort* dp = dst + (size_t)(nb + r) * Kd + kb + c;
#pragma unroll
    for (int i = 0; i < 16; i += 8) {
        short8 o;
#pragma unroll
        for (int j = 0; j < 8; j++) o[j] = (short)tile[c + i + j][r];
        *(short8*)(dp + i) = o;
    }
}

__global__ __launch_bounds__(256)
void prep(const float* __restrict__ x, const float* __restrict__ q_w,
          const float* __restrict__ kv_w, const float* __restrict__ o_w,
          ushort* __restrict__ xb, ushort* __restrict__ wqkvT, ushort* __restrict__ woT)
{
    const int bid = blockIdx.x;
    if (bid < 2048) {                       // cvtx: 2048 blocks
        int i = (bid * 256 + threadIdx.x) * 8;
        float4 a = *(const float4*)(x + i);
        float4 b = *(const float4*)(x + i + 4);
        short8 o;
        o[0] = (short)f2bf(a.x); o[1] = (short)f2bf(a.y);
        o[2] = (short)f2bf(a.z); o[3] = (short)f2bf(a.w);
        o[4] = (short)f2bf(b.x); o[5] = (short)f2bf(b.y);
        o[6] = (short)f2bf(b.z); o[7] = (short)f2bf(b.w);
        *(short8*)(xb + i) = o;
    } else if (bid < 2304) {                // q_w: 16x16
        int r = bid - 2048;
        tcvt_tile(q_w, wqkvT, 1024, 1024, (r & 15) * 64, (r >> 4) * 64);
    } else if (bid < 2816) {                // kv_w: 16x32
        int r = bid - 2304;
        tcvt_tile(kv_w, wqkvT + 1024 * 1024, 1024, 2048, (r & 15) * 64, (r >> 4) * 64);
    } else {                                // o_w: 16x16
        int r = bid - 2816;
        tcvt_tile(o_w, woT, 1024, 1024, (r & 15) * 64, (r >> 4) * 64);
    }
}

// ---------------- 128x128 bf16 MFMA GEMM (R13-proven form, unchanged) ----------------
template<int MODE>
__global__ __launch_bounds__(256)
void gemm128(const ushort* __restrict__ A, const ushort* __restrict__ Bt,
             const float* __restrict__ bias0, const float* __restrict__ bias1,
             ushort* __restrict__ Qo, ushort* __restrict__ Ko, ushort* __restrict__ VoT,
             float* __restrict__ Fo, int Kdim)
{
    __shared__ ushort Al[2][128 * 32];
    __shared__ ushort Bl[2][128 * 32];
    const int tid = threadIdx.x;
    const int lane = tid & 63, w = tid >> 6;
    const int wr = (w >> 1) * 64, wc = (w & 1) * 64;
    const int lg = lane >> 4, lc = lane & 15;

    const int nwg = gridDim.x;
    const int cpx = nwg >> 3;
    const int sid = (blockIdx.x & 7) * cpx + (blockIdx.x >> 3);
    const int bm = (sid & 31) * 128, bn = (sid >> 5) * 128;

    f32x4 acc[4][4] = {};

    const int srow = lane >> 2, scol = (lane & 3) * 8;
    const int seg0 = w * 2;

    const ushort* apb = A  + (size_t)(bm + seg0 * 16 + srow) * Kdim + scol;
    const ushort* bpb = Bt + (size_t)(bn + seg0 * 16 + srow) * Kdim + scol;

    gload16(apb,              &Al[0][seg0 * 512]);
    gload16(apb + 16 * Kdim,  &Al[0][(seg0 + 1) * 512]);
    gload16(bpb,              &Bl[0][seg0 * 512]);
    gload16(bpb + 16 * Kdim,  &Bl[0][(seg0 + 1) * 512]);

    int cur = 0;
    for (int k0 = 0; k0 < Kdim; k0 += 32) {
        __syncthreads();
        if (k0 + 32 < Kdim) {
            gload16(apb + (k0 + 32),             &Al[cur ^ 1][seg0 * 512]);
            gload16(apb + (k0 + 32) + 16 * Kdim, &Al[cur ^ 1][(seg0 + 1) * 512]);
            gload16(bpb + (k0 + 32),             &Bl[cur ^ 1][seg0 * 512]);
            gload16(bpb + (k0 + 32) + 16 * Kdim, &Bl[cur ^ 1][(seg0 + 1) * 512]);
        }
        short8 af[4], bfv[4];
#pragma unroll
        for (int mt = 0; mt < 4; mt++) af[mt] = *(const short8*)&Al[cur][(wr + mt*16 + lc) * 32 + lg*8];
#pragma unroll
        for (int nt = 0; nt < 4; nt++) bfv[nt] = *(const short8*)&Bl[cur][(wc + nt*16 + lc) * 32 + lg*8];
        __builtin_amdgcn_s_setprio(1);
#pragma unroll
        for (int mt = 0; mt < 4; mt++)
#pragma unroll
            for (int nt = 0; nt < 4; nt++)
                acc[mt][nt] = __builtin_amdgcn_mfma_f32_16x16x32_bf16(af[mt], bfv[nt], acc[mt][nt], 0, 0, 0);
        __builtin_amdgcn_s_setprio(0);
        cur ^= 1;
    }

#pragma unroll
    for (int mt = 0; mt < 4; mt++) {
#pragma unroll
        for (int nt = 0; nt < 4; nt++) {
            const int n = bn + wc + nt * 16 + lc;
            const int mb = bm + wr + mt * 16 + lg * 4;
            if (MODE == 1) {
#pragma unroll
                for (int rr = 0; rr < 4; rr++)
                    Fo[(size_t)(mb + rr) * NC + n] = acc[mt][nt][rr] + bias0[n];
            } else {
                const int b = mb >> 11, t = mb & 2047;
                const int reg = n >> 10;            // 0=Q, 1=K, 2=V (uniform per nt)
                if (reg == 0) {
                    int hh = n >> 6, d = n & 63;
                    ushort* qp = Qo + (((size_t)b * NHD + hh) * NT + t) * HDD + d;
#pragma unroll
                    for (int rr = 0; rr < 4; rr++)
                        qp[rr * HDD] = f2bf((acc[mt][nt][rr] + bias0[n]) * (0.125f * LOG2E));
                } else if (reg == 1) {
                    int j = n - NC;
                    int hh = j >> 6, d = j & 63;
                    ushort* kp = Ko + (((size_t)b * NHD + hh) * NT + t) * HDD + d;
#pragma unroll
                    for (int rr = 0; rr < 4; rr++)
                        kp[rr * HDD] = f2bf(acc[mt][nt][rr] + bias1[j]);
                } else {                            // V -> transposed, packed store
                    int j = n - NC;
                    int jj = j - 1024;
                    int hh = jj >> 6, d = jj & 63;
                    short4v o;
#pragma unroll
                    for (int rr = 0; rr < 4; rr++)
                        o[rr] = (short)f2bf(acc[mt][nt][rr] + bias1[j]);
                    *(short4v*)&VoT[(((size_t)b * NHD + hh) * HDD + d) * NT + t] = o;
                }
            }
        }
    }
}

// ---------------- flash attention: 8 waves x 32q = 256 q/block, R13 per-wave body ----------------
// 20 slots x 32 bh = 640 blocks x 512 threads. Staged tiles per bh: 272 -> 144.
// Per-wave register pressure IDENTICAL to R13 (VGPR 80, no spill): 2x f32x16 acc,
// 1 qf set. (R14/R15's 2-qtile-per-wave variant spilled; this shares LDS tiles
// across 8 waves instead.)
__global__ __launch_bounds__(512)
void attn_fwd(const ushort* __restrict__ Q, const ushort* __restrict__ K,
              const ushort* __restrict__ Vt, ushort* __restrict__ Y,
              ushort* __restrict__ pool0, ushort* __restrict__ pool1,
              float* __restrict__ mlb)
{
    __shared__ ushort sb[2 * 2 * 64 * 72];        // 2 buffers x (K + V^T); reused as 8x[32][72] epilogue

    const int tid = threadIdx.x;
    const int lane = tid & 63, w = tid >> 6;      // 8 waves
    const int lo5 = lane & 31, hi = lane >> 5;
    const int slot = (int)(blockIdx.x >> 5);
    const int bh = blockIdx.x & 31;
    const int b = bh >> 4, h = bh & 15;

    // slot -> (qc, seg, nseg); heavy-first. qc = 256-row q chunk.
    int qc, seg, nseg;
    if (slot < 8)       { qc = 7 - (slot >> 2); seg = slot & 3; nseg = 4; }
    else if (slot < 14) { int u = slot - 8; int q3 = u / 3; qc = 5 - q3; seg = u - q3 * 3; nseg = 3; }
    else if (slot < 18) { int u = slot - 14; qc = 3 - (u >> 1); seg = u & 1; nseg = 2; }
    else                { qc = 19 - slot; seg = 0; nseg = 1; }
    const int T = 4 * qc + 4;
    const int t_begin = (seg * T) / nseg;
    const int t_end   = ((seg + 1) * T) / nseg;
    const bool split = (nseg > 1);
    int pi = 0;
    if (split) {
        int pbase = (qc == 7) ? 0 : (qc == 6) ? 4 : (qc == 5) ? 8 : (qc == 4) ? 11 : (qc == 3) ? 14 : 16;
        pi = bh * 18 + pbase + seg;
    }

    const ushort* Qp = Q + (size_t)bh * NT * HDD;
    const ushort* Kp = K + (size_t)bh * NT * HDD;
    const ushort* Vp = Vt + (size_t)bh * HDD * NT;

    const int q0 = qc * 256 + w * 32;             // wave's 32 q rows
    const int qlane = q0 + lo5;

    const float slope2 = (float)(h + 1) * (LOG2E / (float)NHD);

    short8 qf[4];
    {
        const ushort* qr = Qp + (size_t)qlane * HDD + 8 * hi;
#pragma unroll
        for (int kk = 0; kk < 4; kk++) qf[kk] = *(const short8*)(qr + kk * 16);
    }

    short8 ones;
#pragma unroll
    for (int j = 0; j < 8; j++) ones[j] = (short)0x3F80;

    float bb[16];
#pragma unroll
    for (int r = 0; r < 16; r++) {
        int roff = (r & 3) + 8 * (r >> 2) + 4 * hi;
        bb[r] = slope2 * ((float)roff - (float)qlane);
    }

    float m_s = -1e30f, l_s = 0.f;
    f32x16 accO[2] = {};

    // staging: 512 threads, 64 rows x 8 col-chunks of 8 ushorts (16B each)
    const int sr = tid >> 3, sd = (tid & 7) * 8;

    // prefetch first tile (1 short8 K + 1 short8 V per thread)
    short8 pk, pv;
    {
        pk = *(const short8*)(Kp + (size_t)(t_begin * 64 + sr) * HDD + sd);
        pv = *(const short8*)(Vp + (size_t)sr * NT + t_begin * 64 + sd);
    }

    for (int t = t_begin; t < t_end; t++) {
        const int kv0 = t * 64;
        ushort* Kl = sb + ((t - t_begin) & 1) * 2 * 64 * 72;
        ushort* Vl = Kl + 64 * 72;
        *(short8*)&Kl[sr * 72 + sd] = pk;
        *(short8*)&Vl[sr * 72 + sd] = pv;
        __syncthreads();                          // single barrier per tile (dbuf)

        if (t + 1 < t_end) {
            const int kv1 = kv0 + 64;
            pk = *(const short8*)(Kp + (size_t)(kv1 + sr) * HDD + sd);
            pv = *(const short8*)(Vp + (size_t)sr * NT + kv1 + sd);
        }

#pragma unroll
        for (int sub = 0; sub < 2; sub++) {
            const int kv0s = kv0 + sub * 32;
            if (kv0s > q0 + 31) continue;          // wave-uniform skip past diagonal

            // ---- QK^T: S^T[kv][q] ----
            f32x16 S = {};
            __builtin_amdgcn_s_setprio(1);
#pragma unroll
            for (int kk = 0; kk < 4; kk++) {
                short8 kf = *(const short8*)&Kl[(sub * 32 + lo5) * 72 + kk * 16 + 8 * hi];
                S = __builtin_amdgcn_mfma_f32_32x32x16_bf16(kf, qf[kk], S, 0, 0, 0);
            }
            __builtin_amdgcn_s_setprio(0);

            const float sk = slope2 * (float)kv0s;
            float mloc = m_s - sk;

            if (kv0s + 31 > q0) {                  // diagonal sub-block: mask
#pragma unroll
                for (int r = 0; r < 16; r++) {
                    int kvr = kv0s + (r & 3) + 8 * (r >> 2) + 4 * hi;
                    S[r] = (kvr > qlane) ? -1e30f : (S[r] + bb[r]);
                }
            } else {
#pragma unroll
                for (int r = 0; r < 16; r++) S[r] = S[r] + bb[r];
            }

            // tree max, max3-grouped (T17)
            float a0 = fmaxf(fmaxf(S[0], S[1]), S[2]);
            float a1 = fmaxf(fmaxf(S[3], S[4]), S[5]);
            float a2 = fmaxf(fmaxf(S[6], S[7]), S[8]);
            float a3 = fmaxf(fmaxf(S[9], S[10]), S[11]);
            float a4 = fmaxf(fmaxf(S[12], S[13]), S[14]);
            float rmax = fmaxf(fmaxf(fmaxf(a0, a1), fmaxf(a2, a3)), fmaxf(a4, S[15]));
            rmax = fmaxf(rmax, __shfl_xor(rmax, 32));

            if (__any(rmax - mloc > 8.0f)) {       // defer-max (T13)
                float mn = fmaxf(mloc, rmax);
                float sc = __builtin_amdgcn_exp2f(mloc - mn);
                mloc = mn;
                l_s *= sc;
#pragma unroll
                for (int dt = 0; dt < 2; dt++)
#pragma unroll
                    for (int r = 0; r < 16; r++) accO[dt][r] *= sc;
            }
            m_s = mloc + sk;

#pragma unroll
            for (int r = 0; r < 16; r++)           // reuse S regs for p
                S[r] = __builtin_amdgcn_exp2f(S[r] - mloc);

            // ---- P -> bf16 PV B-fragments via permlane32_swap (T12) ----
            unsigned pw[8];
#pragma unroll
            for (int i = 0; i < 8; i++) pw[i] = pkbf(S[2 * i], S[2 * i + 1]);
            asm volatile("v_permlane32_swap_b32 %0, %1" : "+v"(pw[0]), "+v"(pw[2]));
            asm volatile("v_permlane32_swap_b32 %0, %1" : "+v"(pw[1]), "+v"(pw[3]));
            asm volatile("v_permlane32_swap_b32 %0, %1" : "+v"(pw[4]), "+v"(pw[6]));
            asm volatile("v_permlane32_swap_b32 %0, %1" : "+v"(pw[5]), "+v"(pw[7]));
            union { unsigned u[4]; short8 s; } fa0, fa1;
            fa0.u[0] = pw[0]; fa0.u[1] = pw[1]; fa0.u[2] = pw[2]; fa0.u[3] = pw[3];
            fa1.u[0] = pw[4]; fa1.u[1] = pw[5]; fa1.u[2] = pw[6]; fa1.u[3] = pw[7];

            // ---- row-sum via MFMA-ones ----
            f32x16 z = {};
            __builtin_amdgcn_s_setprio(1);
            z = __builtin_amdgcn_mfma_f32_32x32x16_bf16(ones, fa0.s, z, 0, 0, 0);
            z = __builtin_amdgcn_mfma_f32_32x32x16_bf16(ones, fa1.s, z, 0, 0, 0);

            // ---- PV: O^T[d][q] += V^T x P ----
#pragma unroll
            for (int dt = 0; dt < 2; dt++) {
                short8 vf0 = *(const short8*)&Vl[(dt * 32 + lo5) * 72 + sub * 32 + 8 * hi];
                short8 vf1 = *(const short8*)&Vl[(dt * 32 + lo5) * 72 + sub * 32 + 16 + 8 * hi];
                accO[dt] = __builtin_amdgcn_mfma_f32_32x32x16_bf16(vf0, fa0.s, accO[dt], 0, 0, 0);
                accO[dt] = __builtin_amdgcn_mfma_f32_32x32x16_bf16(vf1, fa1.s, accO[dt], 0, 0, 0);
            }
            __builtin_amdgcn_s_setprio(0);

            l_s += z[0];
        }
    }

    // ---- epilogue ----
    const float invl = split ? 1.0f : __builtin_amdgcn_rcpf(l_s);
    __syncthreads();
    ushort* myO = sb + w * 32 * 72;               // 8 waves x [32 q][72] = exactly sb
#pragma unroll
    for (int dt = 0; dt < 2; dt++)
#pragma unroll
        for (int r = 0; r < 16; r++) {
            int d = dt * 32 + (r & 3) + 8 * (r >> 2) + 4 * hi;
            myO[lo5 * 72 + d] = f2bf(accO[dt][r] * invl);
        }
    if (split && hi == 0) {
        int rowin = w * 32 + lo5;                 // 0..255
        mlb[pi * 512 + rowin]       = m_s;
        mlb[pi * 512 + 256 + rowin] = l_s;
    }
    __syncthreads();
    const int orow = lane >> 1, ocol = (lane & 1) * 32;
    const int row = w * 32 + orow;                // 0..255 within block
    if (split) {
        ushort* pp = (pi < 192 ? pool0 + (size_t)pi * 16384
                               : pool1 + (size_t)(pi - 192) * 16384)
                     + row * 64 + ocol;
#pragma unroll
        for (int c = 0; c < 4; c++)
            *(short8*)(pp + c * 8) = *(const short8*)&myO[orow * 72 + ocol + c * 8];
    } else {
        ushort* yp = Y + ((size_t)b * NT + q0 + orow) * NC + h * HDD + ocol;
#pragma unroll
        for (int c = 0; c < 4; c++)
            *(short8*)(yp + c * 8) = *(const short8*)&myO[orow * 72 + ocol + c * 8];
    }
}

// ---------------- combine split-KV partials (2-4 parts, 256 rows) ----------------
// grid 192: one block per (bh, qc in [2,7])
__global__ __launch_bounds__(256)
void combine(const ushort* __restrict__ pool0, const ushort* __restrict__ pool1,
             const float* __restrict__ mlb, ushort* __restrict__ Y)
{
    const int cb = blockIdx.x;
    const int bh = cb / 6, qs = cb % 6;
    const int qc = 7 - qs;
    const int b = bh >> 4, h = bh & 15;
    const int nseg = (qs < 2) ? 4 : (qs < 4) ? 3 : 2;
    const int pbase = (qs == 0) ? 0 : (qs == 1) ? 4 : (qs == 2) ? 8 : (qs == 3) ? 11 : (qs == 4) ? 14 : 16;
    const int pi0 = bh * 18 + pbase;

    const int r = threadIdx.x;                    // 0..255 rows

    float m[4], l[4], a[4];
    float M = -1e30f;
    for (int s = 0; s < nseg; s++) {
        m[s] = mlb[(pi0 + s) * 512 + r];
        l[s] = mlb[(pi0 + s) * 512 + 256 + r];
        M = fmaxf(M, m[s]);
    }
    float L = 0.f;
    for (int s = 0; s < nseg; s++) { a[s] = __builtin_amdgcn_exp2f(m[s] - M); L += a[s] * l[s]; }
    const float inv = __builtin_amdgcn_rcpf(L);

    const ushort* pp[4];
    for (int s = 0; s < nseg; s++) {
        int pi = pi0 + s;
        pp[s] = (pi < 192 ? pool0 + (size_t)pi * 16384 : pool1 + (size_t)(pi - 192) * 16384) + r * 64;
    }
    ushort* yp = Y + ((size_t)b * NT + qc * 256 + r) * NC + h * HDD;

#pragma unroll
    for (int c = 0; c < 8; c++) {
        float acc[8] = {};
        for (int s = 0; s < nseg; s++) {
            short8 u = *(const short8*)(pp[s] + c * 8);
#pragma unroll
            for (int j = 0; j < 8; j++) acc[j] += a[s] * bf2f((ushort)u[j]);
        }
        short8 o;
#pragma unroll
        for (int j = 0; j < 8; j++) o[j] = (short)f2bf(acc[j] * inv);
        *(short8*)(yp + c * 8) = o;
    }
}

extern "C" void kernel_launch(void* const* d_in, const int* in_sizes, int n_in,
                              void* d_out, int out_size, void* d_ws, size_t ws_size,
                              hipStream_t stream)
{
    const float* x    = (const float*)d_in[0];
    const float* q_w  = (const float*)d_in[1];
    const float* q_b  = (const float*)d_in[2];
    const float* kv_w = (const float*)d_in[3];
    const float* kv_b = (const float*)d_in[4];
    const float* o_w  = (const float*)d_in[5];
    const float* o_b  = (const float*)d_in[6];
    float* out = (float*)d_out;

    char* ws = (char*)d_ws;
    ushort* xb    = (ushort*)(ws);                 // 8 MB (x bf16; read by gemm0)
    ushort* wqkvT = (ushort*)(ws + 8388608);       // 6 MB (weights; reused: pool0, 192x32KB)
    ushort* woT   = (ushort*)(ws + 14680064);      // 2 MB
    ushort* Qs    = (ushort*)(ws + 16777216);
    ushort* Ks    = (ushort*)(ws + 25165824);
    ushort* VsT   = (ushort*)(ws + 33554432);      // 8 MB: V^T written by gemm0 epilogue
    ushort* Ys    = (ushort*)(ws + 41943040);
    ushort* pool0 = wqkvT;                         // 192 slots x 32KB (6 MB exactly)
    ushort* pool1 = (ushort*)out;                  // 384 slots x 32KB in d_out (12 MB)
    float*  mlb   = (float*)((char*)out + 12582912);   // 576 x 512 f32 (1.2 MB)

    prep<<<3072, 256, 0, stream>>>(x, q_w, kv_w, o_w, xb, wqkvT, woT);
    gemm128<0><<<768, 256, 0, stream>>>(xb, wqkvT, q_b, kv_b, Qs, Ks, VsT, nullptr, 1024);
    attn_fwd<<<640, 512, 0, stream>>>(Qs, Ks, VsT, Ys, pool0, pool1, mlb);
    combine<<<192, 256, 0, stream>>>(pool0, pool1, mlb, Ys);
    gemm128<1><<<256, 256, 0, stream>>>(Ys, woT, o_b, nullptr, nullptr, nullptr, nullptr, out, 1024);
}

// Round 18
// 132.493 us; speedup vs baseline: 1.6726x; 1.1133x over previous
//
#include <hip/hip_runtime.h>
#include <hip/hip_bf16.h>

#define NB 2
#define NT 2048
#define NC 1024
#define NHD 16
#define HDD 64
#define LOG2E 1.4426950408889634f

typedef __attribute__((ext_vector_type(8))) short short8;
typedef __attribute__((ext_vector_type(4))) short short4v;
typedef __attribute__((ext_vector_type(4))) float f32x4;
typedef __attribute__((ext_vector_type(16))) float f32x16;

__device__ __forceinline__ ushort f2bf(float f) {
    union { float f; unsigned u; } v; v.f = f;
    unsigned u = v.u;
    unsigned r = (u + 0x7FFFu + ((u >> 16) & 1u)) >> 16;
    return (ushort)r;
}

__device__ __forceinline__ float bf2f(ushort u) {
    unsigned x = ((unsigned)u) << 16;
    float f; __builtin_memcpy(&f, &x, 4); return f;
}

__device__ __forceinline__ unsigned pkbf(float a, float b) {
    __hip_bfloat162 t = __float22bfloat162_rn(float2{a, b});
    unsigned u; __builtin_memcpy(&u, &t, 4); return u;
}

__device__ __forceinline__ void gload16(const ushort* g, ushort* l) {
    __builtin_amdgcn_global_load_lds((const __attribute__((address_space(1))) void*)g,
                                     (__attribute__((address_space(3))) void*)l, 16, 0, 0);
}

// ---------------- fused prep: x->bf16 + 3 weight transposes ----------------
__device__ __forceinline__ void tcvt_tile(const float* __restrict__ src, ushort* __restrict__ dst,
                                          int Kd, int Nd, int kb, int nb)
{
    __shared__ ushort tile[64][68];
    const int tid = threadIdx.x;
    const int r = tid >> 2, c = (tid & 3) * 16;
    const float* sp = src + (size_t)(kb + r) * Nd + nb + c;
#pragma unroll
    for (int i = 0; i < 16; i += 4) {
        float4 v = *(const float4*)(sp + i);
        tile[r][c + i + 0] = f2bf(v.x);
        tile[r][c + i + 1] = f2bf(v.y);
        tile[r][c + i + 2] = f2bf(v.z);
        tile[r][c + i + 3] = f2bf(v.w);
    }
    __syncthreads();
    ushort* dp = dst + (size_t)(nb + r) * Kd + kb + c;
#pragma unroll
    for (int i = 0; i < 16; i += 8) {
        short8 o;
#pragma unroll
        for (int j = 0; j < 8; j++) o[j] = (short)tile[c + i + j][r];
        *(short8*)(dp + i) = o;
    }
}

__global__ __launch_bounds__(256)
void prep(const float* __restrict__ x, const float* __restrict__ q_w,
          const float* __restrict__ kv_w, const float* __restrict__ o_w,
          ushort* __restrict__ xb, ushort* __restrict__ wqkvT, ushort* __restrict__ woT)
{
    const int bid = blockIdx.x;
    if (bid < 2048) {                       // cvtx: 2048 blocks
        int i = (bid * 256 + threadIdx.x) * 8;
        float4 a = *(const float4*)(x + i);
        float4 b = *(const float4*)(x + i + 4);
        short8 o;
        o[0] = (short)f2bf(a.x); o[1] = (short)f2bf(a.y);
        o[2] = (short)f2bf(a.z); o[3] = (short)f2bf(a.w);
        o[4] = (short)f2bf(b.x); o[5] = (short)f2bf(b.y);
        o[6] = (short)f2bf(b.z); o[7] = (short)f2bf(b.w);
        *(short8*)(xb + i) = o;
    } else if (bid < 2304) {                // q_w: 16x16
        int r = bid - 2048;
        tcvt_tile(q_w, wqkvT, 1024, 1024, (r & 15) * 64, (r >> 4) * 64);
    } else if (bid < 2816) {                // kv_w: 16x32
        int r = bid - 2304;
        tcvt_tile(kv_w, wqkvT + 1024 * 1024, 1024, 2048, (r & 15) * 64, (r >> 4) * 64);
    } else {                                // o_w: 16x16
        int r = bid - 2816;
        tcvt_tile(o_w, woT, 1024, 1024, (r & 15) * 64, (r >> 4) * 64);
    }
}

// ---------------- 128x128 bf16 MFMA GEMM ----------------
// XCD-chunked swizzle (T1), 2-buffer dbuf LDS, single __syncthreads per K-step
// (T3-min). T4 counted-vmcnt REJECTED (R12: -68% — occupancy loss + L2 lockstep
// break outside 8-phase structure). MODE 0 epilogue: Q (scaled), K, V-transposed.
template<int MODE>
__global__ __launch_bounds__(256)
void gemm128(const ushort* __restrict__ A, const ushort* __restrict__ Bt,
             const float* __restrict__ bias0, const float* __restrict__ bias1,
             ushort* __restrict__ Qo, ushort* __restrict__ Ko, ushort* __restrict__ VoT,
             float* __restrict__ Fo, int Kdim)
{
    __shared__ ushort Al[2][128 * 32];
    __shared__ ushort Bl[2][128 * 32];
    const int tid = threadIdx.x;
    const int lane = tid & 63, w = tid >> 6;
    const int wr = (w >> 1) * 64, wc = (w & 1) * 64;
    const int lg = lane >> 4, lc = lane & 15;

    const int nwg = gridDim.x;
    const int cpx = nwg >> 3;
    const int sid = (blockIdx.x & 7) * cpx + (blockIdx.x >> 3);
    const int bm = (sid & 31) * 128, bn = (sid >> 5) * 128;

    f32x4 acc[4][4] = {};

    const int srow = lane >> 2, scol = (lane & 3) * 8;
    const int seg0 = w * 2;

    const ushort* apb = A  + (size_t)(bm + seg0 * 16 + srow) * Kdim + scol;
    const ushort* bpb = Bt + (size_t)(bn + seg0 * 16 + srow) * Kdim + scol;

    gload16(apb,              &Al[0][seg0 * 512]);
    gload16(apb + 16 * Kdim,  &Al[0][(seg0 + 1) * 512]);
    gload16(bpb,              &Bl[0][seg0 * 512]);
    gload16(bpb + 16 * Kdim,  &Bl[0][(seg0 + 1) * 512]);

    int cur = 0;
    for (int k0 = 0; k0 < Kdim; k0 += 32) {
        __syncthreads();                    // stage(k0) complete (vmcnt drain)
        if (k0 + 32 < Kdim) {               // issue next-tile loads into other buffer
            gload16(apb + (k0 + 32),             &Al[cur ^ 1][seg0 * 512]);
            gload16(apb + (k0 + 32) + 16 * Kdim, &Al[cur ^ 1][(seg0 + 1) * 512]);
            gload16(bpb + (k0 + 32),             &Bl[cur ^ 1][seg0 * 512]);
            gload16(bpb + (k0 + 32) + 16 * Kdim, &Bl[cur ^ 1][(seg0 + 1) * 512]);
        }
        short8 af[4], bfv[4];
#pragma unroll
        for (int mt = 0; mt < 4; mt++) af[mt] = *(const short8*)&Al[cur][(wr + mt*16 + lc) * 32 + lg*8];
#pragma unroll
        for (int nt = 0; nt < 4; nt++) bfv[nt] = *(const short8*)&Bl[cur][(wc + nt*16 + lc) * 32 + lg*8];
        __builtin_amdgcn_s_setprio(1);
#pragma unroll
        for (int mt = 0; mt < 4; mt++)
#pragma unroll
            for (int nt = 0; nt < 4; nt++)
                acc[mt][nt] = __builtin_amdgcn_mfma_f32_16x16x32_bf16(af[mt], bfv[nt], acc[mt][nt], 0, 0, 0);
        __builtin_amdgcn_s_setprio(0);
        cur ^= 1;
    }

#pragma unroll
    for (int mt = 0; mt < 4; mt++) {
#pragma unroll
        for (int nt = 0; nt < 4; nt++) {
            const int n = bn + wc + nt * 16 + lc;
            const int mb = bm + wr + mt * 16 + lg * 4;
            if (MODE == 1) {
#pragma unroll
                for (int rr = 0; rr < 4; rr++)
                    Fo[(size_t)(mb + rr) * NC + n] = acc[mt][nt][rr] + bias0[n];
            } else {
                const int b = mb >> 11, t = mb & 2047;
                const int reg = n >> 10;            // 0=Q, 1=K, 2=V (uniform per nt)
                if (reg == 0) {
                    int hh = n >> 6, d = n & 63;
                    ushort* qp = Qo + (((size_t)b * NHD + hh) * NT + t) * HDD + d;
#pragma unroll
                    for (int rr = 0; rr < 4; rr++)
                        qp[rr * HDD] = f2bf((acc[mt][nt][rr] + bias0[n]) * (0.125f * LOG2E));
                } else if (reg == 1) {
                    int j = n - NC;
                    int hh = j >> 6, d = j & 63;
                    ushort* kp = Ko + (((size_t)b * NHD + hh) * NT + t) * HDD + d;
#pragma unroll
                    for (int rr = 0; rr < 4; rr++)
                        kp[rr * HDD] = f2bf(acc[mt][nt][rr] + bias1[j]);
                } else {                            // V -> transposed, packed store
                    int j = n - NC;
                    int jj = j - 1024;
                    int hh = jj >> 6, d = jj & 63;
                    short4v o;
#pragma unroll
                    for (int rr = 0; rr < 4; rr++)
                        o[rr] = (short)f2bf(acc[mt][nt][rr] + bias1[j]);
                    *(short4v*)&VoT[(((size_t)b * NHD + hh) * HDD + d) * NT + t] = o;
                }
            }
        }
    }
}

// ---------------- flash attention, 32x32 swapped-operand, fine KV-split ----------------
// R13-proven form: 40 slots x 32 bh = 1280 blocks, 4 waves x 32 q = 128 q/block.
// (R14-R16 falsified "more q per staged tile": spills at 64q/wave; 8-wave blocks
// lose scheduling granularity, attn 50->64us. This structure is the floor.)
// permlane32_swap (T12); MFMA-ones row-sum; max3 tree (T17); defer-max (T13).
__global__ __launch_bounds__(256, 3)
void attn_fwd(const ushort* __restrict__ Q, const ushort* __restrict__ K,
              const ushort* __restrict__ Vt, ushort* __restrict__ Y,
              ushort* __restrict__ pool0, ushort* __restrict__ pool1,
              float* __restrict__ mlb)
{
    __shared__ ushort sb[2 * 2 * 64 * 72];        // 2 buffers x (K + V^T)

    const int tid = threadIdx.x;
    const int lane = tid & 63, w = tid >> 6;
    const int lo5 = lane & 31, hi = lane >> 5;
    const int slot = (int)(blockIdx.x >> 5);
    const int bh = blockIdx.x & 31;
    const int b = bh >> 4, h = bh & 15;

    // slot -> (qt, seg, nseg); heavy-first
    int qt, seg, nseg;
    if (slot < 16)      { qt = 15 - (slot >> 2); seg = slot & 3; nseg = 4; }
    else if (slot < 28) { int u = slot - 16; int q3 = u / 3; qt = 11 - q3; seg = u - q3 * 3; nseg = 3; }
    else if (slot < 36) { int u = slot - 28; qt = 7 - (u >> 1); seg = u & 1; nseg = 2; }
    else                { qt = 39 - slot; seg = 0; nseg = 1; }
    const int T = 2 * qt + 2;
    const int t_begin = (seg * T) / nseg;
    const int t_end   = ((seg + 1) * T) / nseg;
    const bool split = (nseg > 1);
    int pi = 0;
    if (split) {
        int pbase = (qt < 8) ? (qt - 4) * 2 : ((qt < 12) ? 8 + (qt - 8) * 3 : 20 + (qt - 12) * 4);
        pi = bh * 36 + pbase + seg;
    }

    const ushort* Qp = Q + (size_t)bh * NT * HDD;
    const ushort* Kp = K + (size_t)bh * NT * HDD;
    const ushort* Vp = Vt + (size_t)bh * HDD * NT;

    const int q0 = qt * 128 + w * 32;
    const int qlane = q0 + lo5;

    const float slope2 = (float)(h + 1) * (LOG2E / (float)NHD);

    short8 qf[4];
    {
        const ushort* qr = Qp + (size_t)qlane * HDD + 8 * hi;
#pragma unroll
        for (int kk = 0; kk < 4; kk++) qf[kk] = *(const short8*)(qr + kk * 16);
    }

    short8 ones;
#pragma unroll
    for (int j = 0; j < 8; j++) ones[j] = (short)0x3F80;

    float bb[16];
#pragma unroll
    for (int r = 0; r < 16; r++) {
        int roff = (r & 3) + 8 * (r >> 2) + 4 * hi;
        bb[r] = slope2 * ((float)roff - (float)qlane);
    }

    float m_s = -1e30f, l_s = 0.f;
    f32x16 accO[2] = {};

    const int sr = tid >> 2, sd = (tid & 3) * 16;

    // prefetch first tile
    short8 pk0, pk1, pv0, pv1;
    {
        const ushort* kp = Kp + (size_t)(t_begin * 64 + sr) * HDD + sd;
        pk0 = *(const short8*)kp;
        pk1 = *(const short8*)(kp + 8);
        const ushort* vp = Vp + (size_t)sr * NT + t_begin * 64 + sd;
        pv0 = *(const short8*)vp;
        pv1 = *(const short8*)(vp + 8);
    }

    for (int t = t_begin; t < t_end; t++) {
        const int kv0 = t * 64;
        ushort* Kl = sb + ((t - t_begin) & 1) * 2 * 64 * 72;
        ushort* Vl = Kl + 64 * 72;
        *(short8*)&Kl[sr * 72 + sd]     = pk0;
        *(short8*)&Kl[sr * 72 + sd + 8] = pk1;
        *(short8*)&Vl[sr * 72 + sd]     = pv0;
        *(short8*)&Vl[sr * 72 + sd + 8] = pv1;
        __syncthreads();                          // single barrier per tile (dbuf)

        if (t + 1 < t_end) {
            const int kv1 = kv0 + 64;
            const ushort* kp = Kp + (size_t)(kv1 + sr) * HDD + sd;
            pk0 = *(const short8*)kp;
            pk1 = *(const short8*)(kp + 8);
            const ushort* vp = Vp + (size_t)sr * NT + kv1 + sd;
            pv0 = *(const short8*)vp;
            pv1 = *(const short8*)(vp + 8);
        }

#pragma unroll
        for (int sub = 0; sub < 2; sub++) {
            const int kv0s = kv0 + sub * 32;
            if (kv0s > q0 + 31) continue;          // wave-uniform skip past diagonal

            // ---- QK^T: S^T[kv][q] ----
            f32x16 S = {};
            __builtin_amdgcn_s_setprio(1);
#pragma unroll
            for (int kk = 0; kk < 4; kk++) {
                short8 kf = *(const short8*)&Kl[(sub * 32 + lo5) * 72 + kk * 16 + 8 * hi];
                S = __builtin_amdgcn_mfma_f32_32x32x16_bf16(kf, qf[kk], S, 0, 0, 0);
            }
            __builtin_amdgcn_s_setprio(0);

            const float sk = slope2 * (float)kv0s;
            float mloc = m_s - sk;

            if (kv0s + 31 > q0) {                  // diagonal sub-block: mask
#pragma unroll
                for (int r = 0; r < 16; r++) {
                    int kvr = kv0s + (r & 3) + 8 * (r >> 2) + 4 * hi;
                    S[r] = (kvr > qlane) ? -1e30f : (S[r] + bb[r]);
                }
            } else {
#pragma unroll
                for (int r = 0; r < 16; r++) S[r] = S[r] + bb[r];
            }

            // tree max, max3-grouped (T17)
            float a0 = fmaxf(fmaxf(S[0], S[1]), S[2]);
            float a1 = fmaxf(fmaxf(S[3], S[4]), S[5]);
            float a2 = fmaxf(fmaxf(S[6], S[7]), S[8]);
            float a3 = fmaxf(fmaxf(S[9], S[10]), S[11]);
            float a4 = fmaxf(fmaxf(S[12], S[13]), S[14]);
            float rmax = fmaxf(fmaxf(fmaxf(a0, a1), fmaxf(a2, a3)), fmaxf(a4, S[15]));
            rmax = fmaxf(rmax, __shfl_xor(rmax, 32));

            if (__any(rmax - mloc > 8.0f)) {       // defer-max (T13)
                float mn = fmaxf(mloc, rmax);
                float sc = __builtin_amdgcn_exp2f(mloc - mn);
                mloc = mn;
                l_s *= sc;
#pragma unroll
                for (int dt = 0; dt < 2; dt++)
#pragma unroll
                    for (int r = 0; r < 16; r++) accO[dt][r] *= sc;
            }
            m_s = mloc + sk;

#pragma unroll
            for (int r = 0; r < 16; r++)           // reuse S regs for p
                S[r] = __builtin_amdgcn_exp2f(S[r] - mloc);

            // ---- P -> bf16 PV B-fragments via permlane32_swap (T12) ----
            unsigned pw[8];
#pragma unroll
            for (int i = 0; i < 8; i++) pw[i] = pkbf(S[2 * i], S[2 * i + 1]);
            asm volatile("v_permlane32_swap_b32 %0, %1" : "+v"(pw[0]), "+v"(pw[2]));
            asm volatile("v_permlane32_swap_b32 %0, %1" : "+v"(pw[1]), "+v"(pw[3]));
            asm volatile("v_permlane32_swap_b32 %0, %1" : "+v"(pw[4]), "+v"(pw[6]));
            asm volatile("v_permlane32_swap_b32 %0, %1" : "+v"(pw[5]), "+v"(pw[7]));
            union { unsigned u[4]; short8 s; } fa0, fa1;
            fa0.u[0] = pw[0]; fa0.u[1] = pw[1]; fa0.u[2] = pw[2]; fa0.u[3] = pw[3];
            fa1.u[0] = pw[4]; fa1.u[1] = pw[5]; fa1.u[2] = pw[6]; fa1.u[3] = pw[7];

            // ---- row-sum via MFMA-ones ----
            f32x16 z = {};
            __builtin_amdgcn_s_setprio(1);
            z = __builtin_amdgcn_mfma_f32_32x32x16_bf16(ones, fa0.s, z, 0, 0, 0);
            z = __builtin_amdgcn_mfma_f32_32x32x16_bf16(ones, fa1.s, z, 0, 0, 0);

            // ---- PV: O^T[d][q] += V^T x P ----
#pragma unroll
            for (int dt = 0; dt < 2; dt++) {
                short8 vf0 = *(const short8*)&Vl[(dt * 32 + lo5) * 72 + sub * 32 + 8 * hi];
                short8 vf1 = *(const short8*)&Vl[(dt * 32 + lo5) * 72 + sub * 32 + 16 + 8 * hi];
                accO[dt] = __builtin_amdgcn_mfma_f32_32x32x16_bf16(vf0, fa0.s, accO[dt], 0, 0, 0);
                accO[dt] = __builtin_amdgcn_mfma_f32_32x32x16_bf16(vf1, fa1.s, accO[dt], 0, 0, 0);
            }
            __builtin_amdgcn_s_setprio(0);

            l_s += z[0];
        }
    }

    // ---- epilogue ----
    const float invl = split ? 1.0f : __builtin_amdgcn_rcpf(l_s);
    __syncthreads();
    ushort* myO = sb + w * 32 * 72;
#pragma unroll
    for (int dt = 0; dt < 2; dt++)
#pragma unroll
        for (int r = 0; r < 16; r++) {
            int d = dt * 32 + (r & 3) + 8 * (r >> 2) + 4 * hi;
            myO[lo5 * 72 + d] = f2bf(accO[dt][r] * invl);
        }
    if (split && hi == 0) {
        int rowin = w * 32 + lo5;
        mlb[pi * 256 + rowin] = m_s;
        mlb[pi * 256 + 128 + rowin] = l_s;
    }
    __syncthreads();
    const int orow = lane >> 1, ocol = (lane & 1) * 32;
    if (split) {
        ushort* pp = (pi < 320 ? pool0 + (size_t)pi * 8192 : pool1 + (size_t)(pi - 320) * 8192)
                     + (w * 32 + orow) * 64 + ocol;
#pragma unroll
        for (int c = 0; c < 4; c++)
            *(short8*)(pp + c * 8) = *(const short8*)&myO[orow * 72 + ocol + c * 8];
    } else {
        ushort* yp = Y + ((size_t)b * NT + q0 + orow) * NC + h * HDD + ocol;
#pragma unroll
        for (int c = 0; c < 4; c++)
            *(short8*)(yp + c * 8) = *(const short8*)&myO[orow * 72 + ocol + c * 8];
    }
}

// ---------------- combine split-KV partials (2-4 parts) ----------------
__global__ __launch_bounds__(256)
void combine(const ushort* __restrict__ pool0, const ushort* __restrict__ pool1,
             const float* __restrict__ mlb, ushort* __restrict__ Y)
{
    const int cb = blockIdx.x;
    const int bh = cb / 12, qs = cb % 12;
    const int qt = qs + 4;
    const int b = bh >> 4, h = bh & 15;
    const int nseg = (qs < 4) ? 2 : ((qs < 8) ? 3 : 4);
    const int pbase = (qs < 4) ? qs * 2 : ((qs < 8) ? 8 + (qs - 4) * 3 : 20 + (qs - 8) * 4);
    const int pi0 = bh * 36 + pbase;

    const int tid = threadIdx.x;
    const int r = tid >> 1, c0 = (tid & 1) * 32;

    float m[4], l[4], a[4];
    float M = -1e30f;
    for (int s = 0; s < nseg; s++) {
        m[s] = mlb[(pi0 + s) * 256 + r];
        l[s] = mlb[(pi0 + s) * 256 + 128 + r];
        M = fmaxf(M, m[s]);
    }
    float L = 0.f;
    for (int s = 0; s < nseg; s++) { a[s] = __builtin_amdgcn_exp2f(m[s] - M); L += a[s] * l[s]; }
    const float inv = __builtin_amdgcn_rcpf(L);

    const ushort* pp[4];
    for (int s = 0; s < nseg; s++) {
        int pi = pi0 + s;
        pp[s] = (pi < 320 ? pool0 + (size_t)pi * 8192 : pool1 + (size_t)(pi - 320) * 8192) + r * 64 + c0;
    }
    ushort* yp = Y + ((size_t)b * NT + qt * 128 + r) * NC + h * HDD + c0;

#pragma unroll
    for (int c = 0; c < 4; c++) {
        float acc[8] = {};
        for (int s = 0; s < nseg; s++) {
            short8 u = *(const short8*)(pp[s] + c * 8);
#pragma unroll
            for (int j = 0; j < 8; j++) acc[j] += a[s] * bf2f((ushort)u[j]);
        }
        short8 o;
#pragma unroll
        for (int j = 0; j < 8; j++) o[j] = (short)f2bf(acc[j] * inv);
        *(short8*)(yp + c * 8) = o;
    }
}

extern "C" void kernel_launch(void* const* d_in, const int* in_sizes, int n_in,
                              void* d_out, int out_size, void* d_ws, size_t ws_size,
                              hipStream_t stream)
{
    const float* x    = (const float*)d_in[0];
    const float* q_w  = (const float*)d_in[1];
    const float* q_b  = (const float*)d_in[2];
    const float* kv_w = (const float*)d_in[3];
    const float* kv_b = (const float*)d_in[4];
    const float* o_w  = (const float*)d_in[5];
    const float* o_b  = (const float*)d_in[6];
    float* out = (float*)d_out;

    char* ws = (char*)d_ws;
    ushort* xb    = (ushort*)(ws);                 // 8 MB (x bf16; read by gemm0)
    ushort* wqkvT = (ushort*)(ws + 8388608);       // 6 MB (weights; reused: pool0)
    ushort* woT   = (ushort*)(ws + 14680064);      // 2 MB
    ushort* Qs    = (ushort*)(ws + 16777216);
    ushort* Ks    = (ushort*)(ws + 25165824);
    ushort* VsT   = (ushort*)(ws + 33554432);      // 8 MB: V^T written by gemm0 epilogue
    ushort* Ys    = (ushort*)(ws + 41943040);
    ushort* pool0 = wqkvT;                         // 320 slots x 16KB (5 MB of 6)
    ushort* pool1 = (ushort*)out;                  // 832 slots x 16KB in d_out (13.3 MB)
    float*  mlb   = (float*)((char*)out + 832 * 16384);  // 1152 x 256 f32 (1.2 MB)

    prep<<<3072, 256, 0, stream>>>(x, q_w, kv_w, o_w, xb, wqkvT, woT);
    gemm128<0><<<768, 256, 0, stream>>>(xb, wqkvT, q_b, kv_b, Qs, Ks, VsT, nullptr, 1024);
    attn_fwd<<<1280, 256, 0, stream>>>(Qs, Ks, VsT, Ys, pool0, pool1, mlb);
    combine<<<384, 256, 0, stream>>>(pool0, pool1, mlb, Ys);
    gemm128<1><<<256, 256, 0, stream>>>(Ys, woT, o_b, nullptr, nullptr, nullptr, nullptr, out, 1024);
}

// Round 19
// 132.331 us; speedup vs baseline: 1.6746x; 1.0012x over previous
//
#include <hip/hip_runtime.h>
#include <hip/hip_bf16.h>

#define NB 2
#define NT 2048
#define NC 1024
#define NHD 16
#define HDD 64
#define LOG2E 1.4426950408889634f

typedef __attribute__((ext_vector_type(8))) short short8;
typedef __attribute__((ext_vector_type(4))) short short4v;
typedef __attribute__((ext_vector_type(4))) float f32x4;
typedef __attribute__((ext_vector_type(16))) float f32x16;

__device__ __forceinline__ ushort f2bf(float f) {
    union { float f; unsigned u; } v; v.f = f;
    unsigned u = v.u;
    unsigned r = (u + 0x7FFFu + ((u >> 16) & 1u)) >> 16;
    return (ushort)r;
}

__device__ __forceinline__ float bf2f(ushort u) {
    unsigned x = ((unsigned)u) << 16;
    float f; __builtin_memcpy(&f, &x, 4); return f;
}

__device__ __forceinline__ unsigned pkbf(float a, float b) {
    __hip_bfloat162 t = __float22bfloat162_rn(float2{a, b});
    unsigned u; __builtin_memcpy(&u, &t, 4); return u;
}

__device__ __forceinline__ void gload16(const ushort* g, ushort* l) {
    __builtin_amdgcn_global_load_lds((const __attribute__((address_space(1))) void*)g,
                                     (__attribute__((address_space(3))) void*)l, 16, 0, 0);
}

// ---------------- fused prep: x->bf16 + 3 weight transposes ----------------
__device__ __forceinline__ void tcvt_tile(const float* __restrict__ src, ushort* __restrict__ dst,
                                          int Kd, int Nd, int kb, int nb)
{
    __shared__ ushort tile[64][68];
    const int tid = threadIdx.x;
    const int r = tid >> 2, c = (tid & 3) * 16;
    const float* sp = src + (size_t)(kb + r) * Nd + nb + c;
#pragma unroll
    for (int i = 0; i < 16; i += 4) {
        float4 v = *(const float4*)(sp + i);
        tile[r][c + i + 0] = f2bf(v.x);
        tile[r][c + i + 1] = f2bf(v.y);
        tile[r][c + i + 2] = f2bf(v.z);
        tile[r][c + i + 3] = f2bf(v.w);
    }
    __syncthreads();
    ushort* dp = dst + (size_t)(nb + r) * Kd + kb + c;
#pragma unroll
    for (int i = 0; i < 16; i += 8) {
        short8 o;
#pragma unroll
        for (int j = 0; j < 8; j++) o[j] = (short)tile[c + i + j][r];
        *(short8*)(dp + i) = o;
    }
}

__global__ __launch_bounds__(256)
void prep(const float* __restrict__ x, const float* __restrict__ q_w,
          const float* __restrict__ kv_w, const float* __restrict__ o_w,
          ushort* __restrict__ xb, ushort* __restrict__ wqkvT, ushort* __restrict__ woT)
{
    const int bid = blockIdx.x;
    if (bid < 2048) {                       // cvtx: 2048 blocks
        int i = (bid * 256 + threadIdx.x) * 8;
        float4 a = *(const float4*)(x + i);
        float4 b = *(const float4*)(x + i + 4);
        short8 o;
        o[0] = (short)f2bf(a.x); o[1] = (short)f2bf(a.y);
        o[2] = (short)f2bf(a.z); o[3] = (short)f2bf(a.w);
        o[4] = (short)f2bf(b.x); o[5] = (short)f2bf(b.y);
        o[6] = (short)f2bf(b.z); o[7] = (short)f2bf(b.w);
        *(short8*)(xb + i) = o;
    } else if (bid < 2304) {                // q_w: 16x16
        int r = bid - 2048;
        tcvt_tile(q_w, wqkvT, 1024, 1024, (r & 15) * 64, (r >> 4) * 64);
    } else if (bid < 2816) {                // kv_w: 16x32
        int r = bid - 2304;
        tcvt_tile(kv_w, wqkvT + 1024 * 1024, 1024, 2048, (r & 15) * 64, (r >> 4) * 64);
    } else {                                // o_w: 16x16
        int r = bid - 2816;
        tcvt_tile(o_w, woT, 1024, 1024, (r & 15) * 64, (r >> 4) * 64);
    }
}

// ---------------- 128x128 bf16 MFMA GEMM ----------------
// XCD-chunked swizzle (T1), 2-buffer dbuf LDS, single __syncthreads per K-step
// (T3-min). T4 counted-vmcnt REJECTED (R12: -68% — occupancy loss + L2 lockstep
// break outside 8-phase structure). MODE 0 epilogue: Q (scaled), K, V-transposed.
template<int MODE>
__global__ __launch_bounds__(256)
void gemm128(const ushort* __restrict__ A, const ushort* __restrict__ Bt,
             const float* __restrict__ bias0, const float* __restrict__ bias1,
             ushort* __restrict__ Qo, ushort* __restrict__ Ko, ushort* __restrict__ VoT,
             float* __restrict__ Fo, int Kdim)
{
    __shared__ ushort Al[2][128 * 32];
    __shared__ ushort Bl[2][128 * 32];
    const int tid = threadIdx.x;
    const int lane = tid & 63, w = tid >> 6;
    const int wr = (w >> 1) * 64, wc = (w & 1) * 64;
    const int lg = lane >> 4, lc = lane & 15;

    const int nwg = gridDim.x;
    const int cpx = nwg >> 3;
    const int sid = (blockIdx.x & 7) * cpx + (blockIdx.x >> 3);
    const int bm = (sid & 31) * 128, bn = (sid >> 5) * 128;

    f32x4 acc[4][4] = {};

    const int srow = lane >> 2, scol = (lane & 3) * 8;
    const int seg0 = w * 2;

    const ushort* apb = A  + (size_t)(bm + seg0 * 16 + srow) * Kdim + scol;
    const ushort* bpb = Bt + (size_t)(bn + seg0 * 16 + srow) * Kdim + scol;

    gload16(apb,              &Al[0][seg0 * 512]);
    gload16(apb + 16 * Kdim,  &Al[0][(seg0 + 1) * 512]);
    gload16(bpb,              &Bl[0][seg0 * 512]);
    gload16(bpb + 16 * Kdim,  &Bl[0][(seg0 + 1) * 512]);

    int cur = 0;
    for (int k0 = 0; k0 < Kdim; k0 += 32) {
        __syncthreads();                    // stage(k0) complete (vmcnt drain)
        if (k0 + 32 < Kdim) {               // issue next-tile loads into other buffer
            gload16(apb + (k0 + 32),             &Al[cur ^ 1][seg0 * 512]);
            gload16(apb + (k0 + 32) + 16 * Kdim, &Al[cur ^ 1][(seg0 + 1) * 512]);
            gload16(bpb + (k0 + 32),             &Bl[cur ^ 1][seg0 * 512]);
            gload16(bpb + (k0 + 32) + 16 * Kdim, &Bl[cur ^ 1][(seg0 + 1) * 512]);
        }
        short8 af[4], bfv[4];
#pragma unroll
        for (int mt = 0; mt < 4; mt++) af[mt] = *(const short8*)&Al[cur][(wr + mt*16 + lc) * 32 + lg*8];
#pragma unroll
        for (int nt = 0; nt < 4; nt++) bfv[nt] = *(const short8*)&Bl[cur][(wc + nt*16 + lc) * 32 + lg*8];
        __builtin_amdgcn_s_setprio(1);
#pragma unroll
        for (int mt = 0; mt < 4; mt++)
#pragma unroll
            for (int nt = 0; nt < 4; nt++)
                acc[mt][nt] = __builtin_amdgcn_mfma_f32_16x16x32_bf16(af[mt], bfv[nt], acc[mt][nt], 0, 0, 0);
        __builtin_amdgcn_s_setprio(0);
        cur ^= 1;
    }

#pragma unroll
    for (int mt = 0; mt < 4; mt++) {
#pragma unroll
        for (int nt = 0; nt < 4; nt++) {
            const int n = bn + wc + nt * 16 + lc;
            const int mb = bm + wr + mt * 16 + lg * 4;
            if (MODE == 1) {
#pragma unroll
                for (int rr = 0; rr < 4; rr++)
                    Fo[(size_t)(mb + rr) * NC + n] = acc[mt][nt][rr] + bias0[n];
            } else {
                const int b = mb >> 11, t = mb & 2047;
                const int reg = n >> 10;            // 0=Q, 1=K, 2=V (uniform per nt)
                if (reg == 0) {
                    int hh = n >> 6, d = n & 63;
                    ushort* qp = Qo + (((size_t)b * NHD + hh) * NT + t) * HDD + d;
#pragma unroll
                    for (int rr = 0; rr < 4; rr++)
                        qp[rr * HDD] = f2bf((acc[mt][nt][rr] + bias0[n]) * (0.125f * LOG2E));
                } else if (reg == 1) {
                    int j = n - NC;
                    int hh = j >> 6, d = j & 63;
                    ushort* kp = Ko + (((size_t)b * NHD + hh) * NT + t) * HDD + d;
#pragma unroll
                    for (int rr = 0; rr < 4; rr++)
                        kp[rr * HDD] = f2bf(acc[mt][nt][rr] + bias1[j]);
                } else {                            // V -> transposed, packed store
                    int j = n - NC;
                    int jj = j - 1024;
                    int hh = jj >> 6, d = jj & 63;
                    short4v o;
#pragma unroll
                    for (int rr = 0; rr < 4; rr++)
                        o[rr] = (short)f2bf(acc[mt][nt][rr] + bias1[j]);
                    *(short4v*)&VoT[(((size_t)b * NHD + hh) * HDD + d) * NT + t] = o;
                }
            }
        }
    }
}

// ---------------- flash attention, 32x32 swapped-operand, fine KV-split ----------------
// R13-proven form: 40 slots x 32 bh = 1280 blocks, 4 waves x 32 q = 128 q/block.
// (R14-R16 falsified "more q per staged tile": spills at 64q/wave; 8-wave blocks
// lose scheduling granularity, attn 50->64us. This structure is the floor.)
// permlane32_swap (T12); MFMA-ones row-sum; max3 tree (T17); defer-max (T13).
__global__ __launch_bounds__(256, 3)
void attn_fwd(const ushort* __restrict__ Q, const ushort* __restrict__ K,
              const ushort* __restrict__ Vt, ushort* __restrict__ Y,
              ushort* __restrict__ pool0, ushort* __restrict__ pool1,
              float* __restrict__ mlb)
{
    __shared__ ushort sb[2 * 2 * 64 * 72];        // 2 buffers x (K + V^T)

    const int tid = threadIdx.x;
    const int lane = tid & 63, w = tid >> 6;
    const int lo5 = lane & 31, hi = lane >> 5;
    const int slot = (int)(blockIdx.x >> 5);
    const int bh = blockIdx.x & 31;
    const int b = bh >> 4, h = bh & 15;

    // slot -> (qt, seg, nseg); heavy-first
    int qt, seg, nseg;
    if (slot < 16)      { qt = 15 - (slot >> 2); seg = slot & 3; nseg = 4; }
    else if (slot < 28) { int u = slot - 16; int q3 = u / 3; qt = 11 - q3; seg = u - q3 * 3; nseg = 3; }
    else if (slot < 36) { int u = slot - 28; qt = 7 - (u >> 1); seg = u & 1; nseg = 2; }
    else                { qt = 39 - slot; seg = 0; nseg = 1; }
    const int T = 2 * qt + 2;
    const int t_begin = (seg * T) / nseg;
    const int t_end   = ((seg + 1) * T) / nseg;
    const bool split = (nseg > 1);
    int pi = 0;
    if (split) {
        int pbase = (qt < 8) ? (qt - 4) * 2 : ((qt < 12) ? 8 + (qt - 8) * 3 : 20 + (qt - 12) * 4);
        pi = bh * 36 + pbase + seg;
    }

    const ushort* Qp = Q + (size_t)bh * NT * HDD;
    const ushort* Kp = K + (size_t)bh * NT * HDD;
    const ushort* Vp = Vt + (size_t)bh * HDD * NT;

    const int q0 = qt * 128 + w * 32;
    const int qlane = q0 + lo5;

    const float slope2 = (float)(h + 1) * (LOG2E / (float)NHD);

    short8 qf[4];
    {
        const ushort* qr = Qp + (size_t)qlane * HDD + 8 * hi;
#pragma unroll
        for (int kk = 0; kk < 4; kk++) qf[kk] = *(const short8*)(qr + kk * 16);
    }

    short8 ones;
#pragma unroll
    for (int j = 0; j < 8; j++) ones[j] = (short)0x3F80;

    float bb[16];
#pragma unroll
    for (int r = 0; r < 16; r++) {
        int roff = (r & 3) + 8 * (r >> 2) + 4 * hi;
        bb[r] = slope2 * ((float)roff - (float)qlane);
    }

    float m_s = -1e30f, l_s = 0.f;
    f32x16 accO[2] = {};

    const int sr = tid >> 2, sd = (tid & 3) * 16;

    // prefetch first tile
    short8 pk0, pk1, pv0, pv1;
    {
        const ushort* kp = Kp + (size_t)(t_begin * 64 + sr) * HDD + sd;
        pk0 = *(const short8*)kp;
        pk1 = *(const short8*)(kp + 8);
        const ushort* vp = Vp + (size_t)sr * NT + t_begin * 64 + sd;
        pv0 = *(const short8*)vp;
        pv1 = *(const short8*)(vp + 8);
    }

    for (int t = t_begin; t < t_end; t++) {
        const int kv0 = t * 64;
        ushort* Kl = sb + ((t - t_begin) & 1) * 2 * 64 * 72;
        ushort* Vl = Kl + 64 * 72;
        *(short8*)&Kl[sr * 72 + sd]     = pk0;
        *(short8*)&Kl[sr * 72 + sd + 8] = pk1;
        *(short8*)&Vl[sr * 72 + sd]     = pv0;
        *(short8*)&Vl[sr * 72 + sd + 8] = pv1;
        __syncthreads();                          // single barrier per tile (dbuf)

        if (t + 1 < t_end) {
            const int kv1 = kv0 + 64;
            const ushort* kp = Kp + (size_t)(kv1 + sr) * HDD + sd;
            pk0 = *(const short8*)kp;
            pk1 = *(const short8*)(kp + 8);
            const ushort* vp = Vp + (size_t)sr * NT + kv1 + sd;
            pv0 = *(const short8*)vp;
            pv1 = *(const short8*)(vp + 8);
        }

#pragma unroll
        for (int sub = 0; sub < 2; sub++) {
            const int kv0s = kv0 + sub * 32;
            if (kv0s > q0 + 31) continue;          // wave-uniform skip past diagonal

            // ---- QK^T: S^T[kv][q] ----
            f32x16 S = {};
            __builtin_amdgcn_s_setprio(1);
#pragma unroll
            for (int kk = 0; kk < 4; kk++) {
                short8 kf = *(const short8*)&Kl[(sub * 32 + lo5) * 72 + kk * 16 + 8 * hi];
                S = __builtin_amdgcn_mfma_f32_32x32x16_bf16(kf, qf[kk], S, 0, 0, 0);
            }
            __builtin_amdgcn_s_setprio(0);

            const float sk = slope2 * (float)kv0s;
            float mloc = m_s - sk;

            if (kv0s + 31 > q0) {                  // diagonal sub-block: mask
#pragma unroll
                for (int r = 0; r < 16; r++) {
                    int kvr = kv0s + (r & 3) + 8 * (r >> 2) + 4 * hi;
                    S[r] = (kvr > qlane) ? -1e30f : (S[r] + bb[r]);
                }
            } else {
#pragma unroll
                for (int r = 0; r < 16; r++) S[r] = S[r] + bb[r];
            }

            // tree max, max3-grouped (T17)
            float a0 = fmaxf(fmaxf(S[0], S[1]), S[2]);
            float a1 = fmaxf(fmaxf(S[3], S[4]), S[5]);
            float a2 = fmaxf(fmaxf(S[6], S[7]), S[8]);
            float a3 = fmaxf(fmaxf(S[9], S[10]), S[11]);
            float a4 = fmaxf(fmaxf(S[12], S[13]), S[14]);
            float rmax = fmaxf(fmaxf(fmaxf(a0, a1), fmaxf(a2, a3)), fmaxf(a4, S[15]));
            rmax = fmaxf(rmax, __shfl_xor(rmax, 32));

            if (__any(rmax - mloc > 8.0f)) {       // defer-max (T13)
                float mn = fmaxf(mloc, rmax);
                float sc = __builtin_amdgcn_exp2f(mloc - mn);
                mloc = mn;
                l_s *= sc;
#pragma unroll
                for (int dt = 0; dt < 2; dt++)
#pragma unroll
                    for (int r = 0; r < 16; r++) accO[dt][r] *= sc;
            }
            m_s = mloc + sk;

#pragma unroll
            for (int r = 0; r < 16; r++)           // reuse S regs for p
                S[r] = __builtin_amdgcn_exp2f(S[r] - mloc);

            // ---- P -> bf16 PV B-fragments via permlane32_swap (T12) ----
            unsigned pw[8];
#pragma unroll
            for (int i = 0; i < 8; i++) pw[i] = pkbf(S[2 * i], S[2 * i + 1]);
            asm volatile("v_permlane32_swap_b32 %0, %1" : "+v"(pw[0]), "+v"(pw[2]));
            asm volatile("v_permlane32_swap_b32 %0, %1" : "+v"(pw[1]), "+v"(pw[3]));
            asm volatile("v_permlane32_swap_b32 %0, %1" : "+v"(pw[4]), "+v"(pw[6]));
            asm volatile("v_permlane32_swap_b32 %0, %1" : "+v"(pw[5]), "+v"(pw[7]));
            union { unsigned u[4]; short8 s; } fa0, fa1;
            fa0.u[0] = pw[0]; fa0.u[1] = pw[1]; fa0.u[2] = pw[2]; fa0.u[3] = pw[3];
            fa1.u[0] = pw[4]; fa1.u[1] = pw[5]; fa1.u[2] = pw[6]; fa1.u[3] = pw[7];

            // ---- row-sum via MFMA-ones ----
            f32x16 z = {};
            __builtin_amdgcn_s_setprio(1);
            z = __builtin_amdgcn_mfma_f32_32x32x16_bf16(ones, fa0.s, z, 0, 0, 0);
            z = __builtin_amdgcn_mfma_f32_32x32x16_bf16(ones, fa1.s, z, 0, 0, 0);

            // ---- PV: O^T[d][q] += V^T x P ----
#pragma unroll
            for (int dt = 0; dt < 2; dt++) {
                short8 vf0 = *(const short8*)&Vl[(dt * 32 + lo5) * 72 + sub * 32 + 8 * hi];
                short8 vf1 = *(const short8*)&Vl[(dt * 32 + lo5) * 72 + sub * 32 + 16 + 8 * hi];
                accO[dt] = __builtin_amdgcn_mfma_f32_32x32x16_bf16(vf0, fa0.s, accO[dt], 0, 0, 0);
                accO[dt] = __builtin_amdgcn_mfma_f32_32x32x16_bf16(vf1, fa1.s, accO[dt], 0, 0, 0);
            }
            __builtin_amdgcn_s_setprio(0);

            l_s += z[0];
        }
    }

    // ---- epilogue ----
    const float invl = split ? 1.0f : __builtin_amdgcn_rcpf(l_s);
    __syncthreads();
    ushort* myO = sb + w * 32 * 72;
#pragma unroll
    for (int dt = 0; dt < 2; dt++)
#pragma unroll
        for (int r = 0; r < 16; r++) {
            int d = dt * 32 + (r & 3) + 8 * (r >> 2) + 4 * hi;
            myO[lo5 * 72 + d] = f2bf(accO[dt][r] * invl);
        }
    if (split && hi == 0) {
        int rowin = w * 32 + lo5;
        mlb[pi * 256 + rowin] = m_s;
        mlb[pi * 256 + 128 + rowin] = l_s;
    }
    __syncthreads();
    const int orow = lane >> 1, ocol = (lane & 1) * 32;
    if (split) {
        ushort* pp = (pi < 320 ? pool0 + (size_t)pi * 8192 : pool1 + (size_t)(pi - 320) * 8192)
                     + (w * 32 + orow) * 64 + ocol;
#pragma unroll
        for (int c = 0; c < 4; c++)
            *(short8*)(pp + c * 8) = *(const short8*)&myO[orow * 72 + ocol + c * 8];
    } else {
        ushort* yp = Y + ((size_t)b * NT + q0 + orow) * NC + h * HDD + ocol;
#pragma unroll
        for (int c = 0; c < 4; c++)
            *(short8*)(yp + c * 8) = *(const short8*)&myO[orow * 72 + ocol + c * 8];
    }
}

// ---------------- combine split-KV partials (2-4 parts) ----------------
__global__ __launch_bounds__(256)
void combine(const ushort* __restrict__ pool0, const ushort* __restrict__ pool1,
             const float* __restrict__ mlb, ushort* __restrict__ Y)
{
    const int cb = blockIdx.x;
    const int bh = cb / 12, qs = cb % 12;
    const int qt = qs + 4;
    const int b = bh >> 4, h = bh & 15;
    const int nseg = (qs < 4) ? 2 : ((qs < 8) ? 3 : 4);
    const int pbase = (qs < 4) ? qs * 2 : ((qs < 8) ? 8 + (qs - 4) * 3 : 20 + (qs - 8) * 4);
    const int pi0 = bh * 36 + pbase;

    const int tid = threadIdx.x;
    const int r = tid >> 1, c0 = (tid & 1) * 32;

    float m[4], l[4], a[4];
    float M = -1e30f;
    for (int s = 0; s < nseg; s++) {
        m[s] = mlb[(pi0 + s) * 256 + r];
        l[s] = mlb[(pi0 + s) * 256 + 128 + r];
        M = fmaxf(M, m[s]);
    }
    float L = 0.f;
    for (int s = 0; s < nseg; s++) { a[s] = __builtin_amdgcn_exp2f(m[s] - M); L += a[s] * l[s]; }
    const float inv = __builtin_amdgcn_rcpf(L);

    const ushort* pp[4];
    for (int s = 0; s < nseg; s++) {
        int pi = pi0 + s;
        pp[s] = (pi < 320 ? pool0 + (size_t)pi * 8192 : pool1 + (size_t)(pi - 320) * 8192) + r * 64 + c0;
    }
    ushort* yp = Y + ((size_t)b * NT + qt * 128 + r) * NC + h * HDD + c0;

#pragma unroll
    for (int c = 0; c < 4; c++) {
        float acc[8] = {};
        for (int s = 0; s < nseg; s++) {
            short8 u = *(const short8*)(pp[s] + c * 8);
#pragma unroll
            for (int j = 0; j < 8; j++) acc[j] += a[s] * bf2f((ushort)u[j]);
        }
        short8 o;
#pragma unroll
        for (int j = 0; j < 8; j++) o[j] = (short)f2bf(acc[j] * inv);
        *(short8*)(yp + c * 8) = o;
    }
}

extern "C" void kernel_launch(void* const* d_in, const int* in_sizes, int n_in,
                              void* d_out, int out_size, void* d_ws, size_t ws_size,
                              hipStream_t stream)
{
    const float* x    = (const float*)d_in[0];
    const float* q_w  = (const float*)d_in[1];
    const float* q_b  = (const float*)d_in[2];
    const float* kv_w = (const float*)d_in[3];
    const float* kv_b = (const float*)d_in[4];
    const float* o_w  = (const float*)d_in[5];
    const float* o_b  = (const float*)d_in[6];
    float* out = (float*)d_out;

    char* ws = (char*)d_ws;
    ushort* xb    = (ushort*)(ws);                 // 8 MB (x bf16; read by gemm0)
    ushort* wqkvT = (ushort*)(ws + 8388608);       // 6 MB (weights; reused: pool0)
    ushort* woT   = (ushort*)(ws + 14680064);      // 2 MB
    ushort* Qs    = (ushort*)(ws + 16777216);
    ushort* Ks    = (ushort*)(ws + 25165824);
    ushort* VsT   = (ushort*)(ws + 33554432);      // 8 MB: V^T written by gemm0 epilogue
    ushort* Ys    = (ushort*)(ws + 41943040);
    ushort* pool0 = wqkvT;                         // 320 slots x 16KB (5 MB of 6)
    ushort* pool1 = (ushort*)out;                  // 832 slots x 16KB in d_out (13.3 MB)
    float*  mlb   = (float*)((char*)out + 832 * 16384);  // 1152 x 256 f32 (1.2 MB)

    prep<<<3072, 256, 0, stream>>>(x, q_w, kv_w, o_w, xb, wqkvT, woT);
    gemm128<0><<<768, 256, 0, stream>>>(xb, wqkvT, q_b, kv_b, Qs, Ks, VsT, nullptr, 1024);
    attn_fwd<<<1280, 256, 0, stream>>>(Qs, Ks, VsT, Ys, pool0, pool1, mlb);
    combine<<<384, 256, 0, stream>>>(pool0, pool1, mlb, Ys);
    gemm128<1><<<256, 256, 0, stream>>>(Ys, woT, o_b, nullptr, nullptr, nullptr, nullptr, out, 1024);
}

// Round 20
// 132.028 us; speedup vs baseline: 1.6785x; 1.0023x over previous
//
#include <hip/hip_runtime.h>
#include <hip/hip_bf16.h>

#define NB 2
#define NT 2048
#define NC 1024
#define NHD 16
#define HDD 64
#define LOG2E 1.4426950408889634f

typedef __attribute__((ext_vector_type(8))) short short8;
typedef __attribute__((ext_vector_type(4))) short short4v;
typedef __attribute__((ext_vector_type(4))) float f32x4;
typedef __attribute__((ext_vector_type(16))) float f32x16;

__device__ __forceinline__ ushort f2bf(float f) {
    union { float f; unsigned u; } v; v.f = f;
    unsigned u = v.u;
    unsigned r = (u + 0x7FFFu + ((u >> 16) & 1u)) >> 16;
    return (ushort)r;
}

__device__ __forceinline__ float bf2f(ushort u) {
    unsigned x = ((unsigned)u) << 16;
    float f; __builtin_memcpy(&f, &x, 4); return f;
}

__device__ __forceinline__ unsigned pkbf(float a, float b) {
    __hip_bfloat162 t = __float22bfloat162_rn(float2{a, b});
    unsigned u; __builtin_memcpy(&u, &t, 4); return u;
}

__device__ __forceinline__ void gload16(const ushort* g, ushort* l) {
    __builtin_amdgcn_global_load_lds((const __attribute__((address_space(1))) void*)g,
                                     (__attribute__((address_space(3))) void*)l, 16, 0, 0);
}

// ---------------- fused prep: x->bf16 + 3 weight transposes ----------------
__device__ __forceinline__ void tcvt_tile(const float* __restrict__ src, ushort* __restrict__ dst,
                                          int Kd, int Nd, int kb, int nb)
{
    __shared__ ushort tile[64][68];
    const int tid = threadIdx.x;
    const int r = tid >> 2, c = (tid & 3) * 16;
    const float* sp = src + (size_t)(kb + r) * Nd + nb + c;
#pragma unroll
    for (int i = 0; i < 16; i += 4) {
        float4 v = *(const float4*)(sp + i);
        tile[r][c + i + 0] = f2bf(v.x);
        tile[r][c + i + 1] = f2bf(v.y);
        tile[r][c + i + 2] = f2bf(v.z);
        tile[r][c + i + 3] = f2bf(v.w);
    }
    __syncthreads();
    ushort* dp = dst + (size_t)(nb + r) * Kd + kb + c;
#pragma unroll
    for (int i = 0; i < 16; i += 8) {
        short8 o;
#pragma unroll
        for (int j = 0; j < 8; j++) o[j] = (short)tile[c + i + j][r];
        *(short8*)(dp + i) = o;
    }
}

__global__ __launch_bounds__(256)
void prep(const float* __restrict__ x, const float* __restrict__ q_w,
          const float* __restrict__ kv_w, const float* __restrict__ o_w,
          ushort* __restrict__ xb, ushort* __restrict__ wqkvT, ushort* __restrict__ woT)
{
    const int bid = blockIdx.x;
    if (bid < 2048) {                       // cvtx: 2048 blocks
        int i = (bid * 256 + threadIdx.x) * 8;
        float4 a = *(const float4*)(x + i);
        float4 b = *(const float4*)(x + i + 4);
        short8 o;
        o[0] = (short)f2bf(a.x); o[1] = (short)f2bf(a.y);
        o[2] = (short)f2bf(a.z); o[3] = (short)f2bf(a.w);
        o[4] = (short)f2bf(b.x); o[5] = (short)f2bf(b.y);
        o[6] = (short)f2bf(b.z); o[7] = (short)f2bf(b.w);
        *(short8*)(xb + i) = o;
    } else if (bid < 2304) {                // q_w: 16x16
        int r = bid - 2048;
        tcvt_tile(q_w, wqkvT, 1024, 1024, (r & 15) * 64, (r >> 4) * 64);
    } else if (bid < 2816) {                // kv_w: 16x32
        int r = bid - 2304;
        tcvt_tile(kv_w, wqkvT + 1024 * 1024, 1024, 2048, (r & 15) * 64, (r >> 4) * 64);
    } else {                                // o_w: 16x16
        int r = bid - 2816;
        tcvt_tile(o_w, woT, 1024, 1024, (r & 15) * 64, (r >> 4) * 64);
    }
}

// ---------------- 128x128 bf16 MFMA GEMM ----------------
// XCD-chunked swizzle (T1), 2-buffer dbuf LDS, single __syncthreads per K-step
// (T3-min). T4 counted-vmcnt REJECTED (R12: -68% — occupancy loss + L2 lockstep
// break outside 8-phase structure). MODE 0 epilogue: Q (scaled), K, V-transposed.
template<int MODE>
__global__ __launch_bounds__(256)
void gemm128(const ushort* __restrict__ A, const ushort* __restrict__ Bt,
             const float* __restrict__ bias0, const float* __restrict__ bias1,
             ushort* __restrict__ Qo, ushort* __restrict__ Ko, ushort* __restrict__ VoT,
             float* __restrict__ Fo, int Kdim)
{
    __shared__ ushort Al[2][128 * 32];
    __shared__ ushort Bl[2][128 * 32];
    const int tid = threadIdx.x;
    const int lane = tid & 63, w = tid >> 6;
    const int wr = (w >> 1) * 64, wc = (w & 1) * 64;
    const int lg = lane >> 4, lc = lane & 15;

    const int nwg = gridDim.x;
    const int cpx = nwg >> 3;
    const int sid = (blockIdx.x & 7) * cpx + (blockIdx.x >> 3);
    const int bm = (sid & 31) * 128, bn = (sid >> 5) * 128;

    f32x4 acc[4][4] = {};

    const int srow = lane >> 2, scol = (lane & 3) * 8;
    const int seg0 = w * 2;

    const ushort* apb = A  + (size_t)(bm + seg0 * 16 + srow) * Kdim + scol;
    const ushort* bpb = Bt + (size_t)(bn + seg0 * 16 + srow) * Kdim + scol;

    gload16(apb,              &Al[0][seg0 * 512]);
    gload16(apb + 16 * Kdim,  &Al[0][(seg0 + 1) * 512]);
    gload16(bpb,              &Bl[0][seg0 * 512]);
    gload16(bpb + 16 * Kdim,  &Bl[0][(seg0 + 1) * 512]);

    int cur = 0;
    for (int k0 = 0; k0 < Kdim; k0 += 32) {
        __syncthreads();                    // stage(k0) complete (vmcnt drain)
        if (k0 + 32 < Kdim) {               // issue next-tile loads into other buffer
            gload16(apb + (k0 + 32),             &Al[cur ^ 1][seg0 * 512]);
            gload16(apb + (k0 + 32) + 16 * Kdim, &Al[cur ^ 1][(seg0 + 1) * 512]);
            gload16(bpb + (k0 + 32),             &Bl[cur ^ 1][seg0 * 512]);
            gload16(bpb + (k0 + 32) + 16 * Kdim, &Bl[cur ^ 1][(seg0 + 1) * 512]);
        }
        short8 af[4], bfv[4];
#pragma unroll
        for (int mt = 0; mt < 4; mt++) af[mt] = *(const short8*)&Al[cur][(wr + mt*16 + lc) * 32 + lg*8];
#pragma unroll
        for (int nt = 0; nt < 4; nt++) bfv[nt] = *(const short8*)&Bl[cur][(wc + nt*16 + lc) * 32 + lg*8];
        __builtin_amdgcn_s_setprio(1);
#pragma unroll
        for (int mt = 0; mt < 4; mt++)
#pragma unroll
            for (int nt = 0; nt < 4; nt++)
                acc[mt][nt] = __builtin_amdgcn_mfma_f32_16x16x32_bf16(af[mt], bfv[nt], acc[mt][nt], 0, 0, 0);
        __builtin_amdgcn_s_setprio(0);
        cur ^= 1;
    }

#pragma unroll
    for (int mt = 0; mt < 4; mt++) {
#pragma unroll
        for (int nt = 0; nt < 4; nt++) {
            const int n = bn + wc + nt * 16 + lc;
            const int mb = bm + wr + mt * 16 + lg * 4;
            if (MODE == 1) {
#pragma unroll
                for (int rr = 0; rr < 4; rr++)
                    Fo[(size_t)(mb + rr) * NC + n] = acc[mt][nt][rr] + bias0[n];
            } else {
                const int b = mb >> 11, t = mb & 2047;
                const int reg = n >> 10;            // 0=Q, 1=K, 2=V (uniform per nt)
                if (reg == 0) {
                    int hh = n >> 6, d = n & 63;
                    ushort* qp = Qo + (((size_t)b * NHD + hh) * NT + t) * HDD + d;
#pragma unroll
                    for (int rr = 0; rr < 4; rr++)
                        qp[rr * HDD] = f2bf((acc[mt][nt][rr] + bias0[n]) * (0.125f * LOG2E));
                } else if (reg == 1) {
                    int j = n - NC;
                    int hh = j >> 6, d = j & 63;
                    ushort* kp = Ko + (((size_t)b * NHD + hh) * NT + t) * HDD + d;
#pragma unroll
                    for (int rr = 0; rr < 4; rr++)
                        kp[rr * HDD] = f2bf(acc[mt][nt][rr] + bias1[j]);
                } else {                            // V -> transposed, packed store
                    int j = n - NC;
                    int jj = j - 1024;
                    int hh = jj >> 6, d = jj & 63;
                    short4v o;
#pragma unroll
                    for (int rr = 0; rr < 4; rr++)
                        o[rr] = (short)f2bf(acc[mt][nt][rr] + bias1[j]);
                    *(short4v*)&VoT[(((size_t)b * NHD + hh) * HDD + d) * NT + t] = o;
                }
            }
        }
    }
}

// ---------------- flash attention, 32x32 swapped-operand, fine KV-split ----------------
// R13-proven form: 40 slots x 32 bh = 1280 blocks, 4 waves x 32 q = 128 q/block.
// (R14-R16 falsified "more q per staged tile": spills at 64q/wave; 8-wave blocks
// lose scheduling granularity, attn 50->64us. This structure is the floor.)
// permlane32_swap (T12); MFMA-ones row-sum; max3 tree (T17); defer-max (T13).
__global__ __launch_bounds__(256, 3)
void attn_fwd(const ushort* __restrict__ Q, const ushort* __restrict__ K,
              const ushort* __restrict__ Vt, ushort* __restrict__ Y,
              ushort* __restrict__ pool0, ushort* __restrict__ pool1,
              float* __restrict__ mlb)
{
    __shared__ ushort sb[2 * 2 * 64 * 72];        // 2 buffers x (K + V^T)

    const int tid = threadIdx.x;
    const int lane = tid & 63, w = tid >> 6;
    const int lo5 = lane & 31, hi = lane >> 5;
    const int slot = (int)(blockIdx.x >> 5);
    const int bh = blockIdx.x & 31;
    const int b = bh >> 4, h = bh & 15;

    // slot -> (qt, seg, nseg); heavy-first
    int qt, seg, nseg;
    if (slot < 16)      { qt = 15 - (slot >> 2); seg = slot & 3; nseg = 4; }
    else if (slot < 28) { int u = slot - 16; int q3 = u / 3; qt = 11 - q3; seg = u - q3 * 3; nseg = 3; }
    else if (slot < 36) { int u = slot - 28; qt = 7 - (u >> 1); seg = u & 1; nseg = 2; }
    else                { qt = 39 - slot; seg = 0; nseg = 1; }
    const int T = 2 * qt + 2;
    const int t_begin = (seg * T) / nseg;
    const int t_end   = ((seg + 1) * T) / nseg;
    const bool split = (nseg > 1);
    int pi = 0;
    if (split) {
        int pbase = (qt < 8) ? (qt - 4) * 2 : ((qt < 12) ? 8 + (qt - 8) * 3 : 20 + (qt - 12) * 4);
        pi = bh * 36 + pbase + seg;
    }

    const ushort* Qp = Q + (size_t)bh * NT * HDD;
    const ushort* Kp = K + (size_t)bh * NT * HDD;
    const ushort* Vp = Vt + (size_t)bh * HDD * NT;

    const int q0 = qt * 128 + w * 32;
    const int qlane = q0 + lo5;

    const float slope2 = (float)(h + 1) * (LOG2E / (float)NHD);

    short8 qf[4];
    {
        const ushort* qr = Qp + (size_t)qlane * HDD + 8 * hi;
#pragma unroll
        for (int kk = 0; kk < 4; kk++) qf[kk] = *(const short8*)(qr + kk * 16);
    }

    short8 ones;
#pragma unroll
    for (int j = 0; j < 8; j++) ones[j] = (short)0x3F80;

    float bb[16];
#pragma unroll
    for (int r = 0; r < 16; r++) {
        int roff = (r & 3) + 8 * (r >> 2) + 4 * hi;
        bb[r] = slope2 * ((float)roff - (float)qlane);
    }

    float m_s = -1e30f, l_s = 0.f;
    f32x16 accO[2] = {};

    const int sr = tid >> 2, sd = (tid & 3) * 16;

    // prefetch first tile
    short8 pk0, pk1, pv0, pv1;
    {
        const ushort* kp = Kp + (size_t)(t_begin * 64 + sr) * HDD + sd;
        pk0 = *(const short8*)kp;
        pk1 = *(const short8*)(kp + 8);
        const ushort* vp = Vp + (size_t)sr * NT + t_begin * 64 + sd;
        pv0 = *(const short8*)vp;
        pv1 = *(const short8*)(vp + 8);
    }

    for (int t = t_begin; t < t_end; t++) {
        const int kv0 = t * 64;
        ushort* Kl = sb + ((t - t_begin) & 1) * 2 * 64 * 72;
        ushort* Vl = Kl + 64 * 72;
        *(short8*)&Kl[sr * 72 + sd]     = pk0;
        *(short8*)&Kl[sr * 72 + sd + 8] = pk1;
        *(short8*)&Vl[sr * 72 + sd]     = pv0;
        *(short8*)&Vl[sr * 72 + sd + 8] = pv1;
        __syncthreads();                          // single barrier per tile (dbuf)

        if (t + 1 < t_end) {
            const int kv1 = kv0 + 64;
            const ushort* kp = Kp + (size_t)(kv1 + sr) * HDD + sd;
            pk0 = *(const short8*)kp;
            pk1 = *(const short8*)(kp + 8);
            const ushort* vp = Vp + (size_t)sr * NT + kv1 + sd;
            pv0 = *(const short8*)vp;
            pv1 = *(const short8*)(vp + 8);
        }

#pragma unroll
        for (int sub = 0; sub < 2; sub++) {
            const int kv0s = kv0 + sub * 32;
            if (kv0s > q0 + 31) continue;          // wave-uniform skip past diagonal

            // ---- QK^T: S^T[kv][q] ----
            f32x16 S = {};
            __builtin_amdgcn_s_setprio(1);
#pragma unroll
            for (int kk = 0; kk < 4; kk++) {
                short8 kf = *(const short8*)&Kl[(sub * 32 + lo5) * 72 + kk * 16 + 8 * hi];
                S = __builtin_amdgcn_mfma_f32_32x32x16_bf16(kf, qf[kk], S, 0, 0, 0);
            }
            __builtin_amdgcn_s_setprio(0);

            const float sk = slope2 * (float)kv0s;
            float mloc = m_s - sk;

            if (kv0s + 31 > q0) {                  // diagonal sub-block: mask
#pragma unroll
                for (int r = 0; r < 16; r++) {
                    int kvr = kv0s + (r & 3) + 8 * (r >> 2) + 4 * hi;
                    S[r] = (kvr > qlane) ? -1e30f : (S[r] + bb[r]);
                }
            } else {
#pragma unroll
                for (int r = 0; r < 16; r++) S[r] = S[r] + bb[r];
            }

            // tree max, max3-grouped (T17)
            float a0 = fmaxf(fmaxf(S[0], S[1]), S[2]);
            float a1 = fmaxf(fmaxf(S[3], S[4]), S[5]);
            float a2 = fmaxf(fmaxf(S[6], S[7]), S[8]);
            float a3 = fmaxf(fmaxf(S[9], S[10]), S[11]);
            float a4 = fmaxf(fmaxf(S[12], S[13]), S[14]);
            float rmax = fmaxf(fmaxf(fmaxf(a0, a1), fmaxf(a2, a3)), fmaxf(a4, S[15]));
            rmax = fmaxf(rmax, __shfl_xor(rmax, 32));

            if (__any(rmax - mloc > 8.0f)) {       // defer-max (T13)
                float mn = fmaxf(mloc, rmax);
                float sc = __builtin_amdgcn_exp2f(mloc - mn);
                mloc = mn;
                l_s *= sc;
#pragma unroll
                for (int dt = 0; dt < 2; dt++)
#pragma unroll
                    for (int r = 0; r < 16; r++) accO[dt][r] *= sc;
            }
            m_s = mloc + sk;

#pragma unroll
            for (int r = 0; r < 16; r++)           // reuse S regs for p
                S[r] = __builtin_amdgcn_exp2f(S[r] - mloc);

            // ---- P -> bf16 PV B-fragments via permlane32_swap (T12) ----
            unsigned pw[8];
#pragma unroll
            for (int i = 0; i < 8; i++) pw[i] = pkbf(S[2 * i], S[2 * i + 1]);
            asm volatile("v_permlane32_swap_b32 %0, %1" : "+v"(pw[0]), "+v"(pw[2]));
            asm volatile("v_permlane32_swap_b32 %0, %1" : "+v"(pw[1]), "+v"(pw[3]));
            asm volatile("v_permlane32_swap_b32 %0, %1" : "+v"(pw[4]), "+v"(pw[6]));
            asm volatile("v_permlane32_swap_b32 %0, %1" : "+v"(pw[5]), "+v"(pw[7]));
            union { unsigned u[4]; short8 s; } fa0, fa1;
            fa0.u[0] = pw[0]; fa0.u[1] = pw[1]; fa0.u[2] = pw[2]; fa0.u[3] = pw[3];
            fa1.u[0] = pw[4]; fa1.u[1] = pw[5]; fa1.u[2] = pw[6]; fa1.u[3] = pw[7];

            // ---- row-sum via MFMA-ones ----
            f32x16 z = {};
            __builtin_amdgcn_s_setprio(1);
            z = __builtin_amdgcn_mfma_f32_32x32x16_bf16(ones, fa0.s, z, 0, 0, 0);
            z = __builtin_amdgcn_mfma_f32_32x32x16_bf16(ones, fa1.s, z, 0, 0, 0);

            // ---- PV: O^T[d][q] += V^T x P ----
#pragma unroll
            for (int dt = 0; dt < 2; dt++) {
                short8 vf0 = *(const short8*)&Vl[(dt * 32 + lo5) * 72 + sub * 32 + 8 * hi];
                short8 vf1 = *(const short8*)&Vl[(dt * 32 + lo5) * 72 + sub * 32 + 16 + 8 * hi];
                accO[dt] = __builtin_amdgcn_mfma_f32_32x32x16_bf16(vf0, fa0.s, accO[dt], 0, 0, 0);
                accO[dt] = __builtin_amdgcn_mfma_f32_32x32x16_bf16(vf1, fa1.s, accO[dt], 0, 0, 0);
            }
            __builtin_amdgcn_s_setprio(0);

            l_s += z[0];
        }
    }

    // ---- epilogue ----
    const float invl = split ? 1.0f : __builtin_amdgcn_rcpf(l_s);
    __syncthreads();
    ushort* myO = sb + w * 32 * 72;
#pragma unroll
    for (int dt = 0; dt < 2; dt++)
#pragma unroll
        for (int r = 0; r < 16; r++) {
            int d = dt * 32 + (r & 3) + 8 * (r >> 2) + 4 * hi;
            myO[lo5 * 72 + d] = f2bf(accO[dt][r] * invl);
        }
    if (split && hi == 0) {
        int rowin = w * 32 + lo5;
        mlb[pi * 256 + rowin] = m_s;
        mlb[pi * 256 + 128 + rowin] = l_s;
    }
    __syncthreads();
    const int orow = lane >> 1, ocol = (lane & 1) * 32;
    if (split) {
        ushort* pp = (pi < 320 ? pool0 + (size_t)pi * 8192 : pool1 + (size_t)(pi - 320) * 8192)
                     + (w * 32 + orow) * 64 + ocol;
#pragma unroll
        for (int c = 0; c < 4; c++)
            *(short8*)(pp + c * 8) = *(const short8*)&myO[orow * 72 + ocol + c * 8];
    } else {
        ushort* yp = Y + ((size_t)b * NT + q0 + orow) * NC + h * HDD + ocol;
#pragma unroll
        for (int c = 0; c < 4; c++)
            *(short8*)(yp + c * 8) = *(const short8*)&myO[orow * 72 + ocol + c * 8];
    }
}

// ---------------- combine split-KV partials (2-4 parts) ----------------
__global__ __launch_bounds__(256)
void combine(const ushort* __restrict__ pool0, const ushort* __restrict__ pool1,
             const float* __restrict__ mlb, ushort* __restrict__ Y)
{
    const int cb = blockIdx.x;
    const int bh = cb / 12, qs = cb % 12;
    const int qt = qs + 4;
    const int b = bh >> 4, h = bh & 15;
    const int nseg = (qs < 4) ? 2 : ((qs < 8) ? 3 : 4);
    const int pbase = (qs < 4) ? qs * 2 : ((qs < 8) ? 8 + (qs - 4) * 3 : 20 + (qs - 8) * 4);
    const int pi0 = bh * 36 + pbase;

    const int tid = threadIdx.x;
    const int r = tid >> 1, c0 = (tid & 1) * 32;

    float m[4], l[4], a[4];
    float M = -1e30f;
    for (int s = 0; s < nseg; s++) {
        m[s] = mlb[(pi0 + s) * 256 + r];
        l[s] = mlb[(pi0 + s) * 256 + 128 + r];
        M = fmaxf(M, m[s]);
    }
    float L = 0.f;
    for (int s = 0; s < nseg; s++) { a[s] = __builtin_amdgcn_exp2f(m[s] - M); L += a[s] * l[s]; }
    const float inv = __builtin_amdgcn_rcpf(L);

    const ushort* pp[4];
    for (int s = 0; s < nseg; s++) {
        int pi = pi0 + s;
        pp[s] = (pi < 320 ? pool0 + (size_t)pi * 8192 : pool1 + (size_t)(pi - 320) * 8192) + r * 64 + c0;
    }
    ushort* yp = Y + ((size_t)b * NT + qt * 128 + r) * NC + h * HDD + c0;

#pragma unroll
    for (int c = 0; c < 4; c++) {
        float acc[8] = {};
        for (int s = 0; s < nseg; s++) {
            short8 u = *(const short8*)(pp[s] + c * 8);
#pragma unroll
            for (int j = 0; j < 8; j++) acc[j] += a[s] * bf2f((ushort)u[j]);
        }
        short8 o;
#pragma unroll
        for (int j = 0; j < 8; j++) o[j] = (short)f2bf(acc[j] * inv);
        *(short8*)(yp + c * 8) = o;
    }
}

extern "C" void kernel_launch(void* const* d_in, const int* in_sizes, int n_in,
                              void* d_out, int out_size, void* d_ws, size_t ws_size,
                              hipStream_t stream)
{
    const float* x    = (const float*)d_in[0];
    const float* q_w  = (const float*)d_in[1];
    const float* q_b  = (const float*)d_in[2];
    const float* kv_w = (const float*)d_in[3];
    const float* kv_b = (const float*)d_in[4];
    const float* o_w  = (const float*)d_in[5];
    const float* o_b  = (const float*)d_in[6];
    float* out = (float*)d_out;

    char* ws = (char*)d_ws;
    ushort* xb    = (ushort*)(ws);                 // 8 MB (x bf16; read by gemm0)
    ushort* wqkvT = (ushort*)(ws + 8388608);       // 6 MB (weights; reused: pool0)
    ushort* woT   = (ushort*)(ws + 14680064);      // 2 MB
    ushort* Qs    = (ushort*)(ws + 16777216);
    ushort* Ks    = (ushort*)(ws + 25165824);
    ushort* VsT   = (ushort*)(ws + 33554432);      // 8 MB: V^T written by gemm0 epilogue
    ushort* Ys    = (ushort*)(ws + 41943040);
    ushort* pool0 = wqkvT;                         // 320 slots x 16KB (5 MB of 6)
    ushort* pool1 = (ushort*)out;                  // 832 slots x 16KB in d_out (13.3 MB)
    float*  mlb   = (float*)((char*)out + 832 * 16384);  // 1152 x 256 f32 (1.2 MB)

    prep<<<3072, 256, 0, stream>>>(x, q_w, kv_w, o_w, xb, wqkvT, woT);
    gemm128<0><<<768, 256, 0, stream>>>(xb, wqkvT, q_b, kv_b, Qs, Ks, VsT, nullptr, 1024);
    attn_fwd<<<1280, 256, 0, stream>>>(Qs, Ks, VsT, Ys, pool0, pool1, mlb);
    combine<<<384, 256, 0, stream>>>(pool0, pool1, mlb, Ys);
    gemm128<1><<<256, 256, 0, stream>>>(Ys, woT, o_b, nullptr, nullptr, nullptr, nullptr, out, 1024);
}